// Round 7
// baseline (1650.502 us; speedup 1.0000x reference)
//
#include <hip/hip_runtime.h>

#define NPTS  4096
#define NB    8
#define TPB   256
#define TPBR  256
#define MBLK  4
#define NSEG  64
#define CHUNK 64      // = NPTS/NSEG = bbox granule size
#define EPSC  1e-9f

#define EXP2(x)  __builtin_amdgcn_exp2f(x)
#define RCPF(x)  __builtin_amdgcn_rcpf(x)
#define SQRTF(x) __builtin_amdgcn_sqrtf(x)

// ---------------------------------------------------------------------------
// Morton bucket sort (4 bits/axis) per (set,b) + per-64-point-granule bboxes.
// Also zeroes dAcc/rAcc (2 contiguous planes) and out[].
// Any permutation of points is exactly correct (cost is a set-pairwise sum).
// ---------------------------------------------------------------------------
__global__ __launch_bounds__(TPB) void sort_kernel(
    const float* __restrict__ x1, const float* __restrict__ x2,
    float4* __restrict__ x1p, float4* __restrict__ x2p,
    float4* __restrict__ bb,            // [2][NB][64][2] (min,max)
    float* __restrict__ zacc,           // dAcc..rAcc contiguous, 2 planes
    float* __restrict__ out)
{
  __shared__ unsigned int   hist[4096];
  __shared__ unsigned short codes[4096];
  __shared__ unsigned int   part[TPB];

  const int set = blockIdx.x, b = blockIdx.y;
  const float* src = set ? x2 : x1;
  float4* dst = set ? x2p : x1p;
  const int tid = threadIdx.x;
  const int bid = b * 2 + set;

  // zero accumulation planes (+ out)
  for (int i = tid; i < 2 * NB * NPTS / 16; i += TPB)
    zacc[(size_t)bid * (2 * NB * NPTS / 16) + i] = 0.f;
  if (set == 0 && tid == 0) out[b] = 0.f;

  for (int i = tid; i < 4096; i += TPB) hist[i] = 0;
  __syncthreads();

  for (int j = 0; j < NPTS / TPB; ++j) {
    int n = j * TPB + tid;
    const float* p = src + ((size_t)b * NPTS + n) * 3;
    int qx = min(max((int)((p[0] + 4.f) * 2.f), 0), 15);
    int qy = min(max((int)((p[1] + 4.f) * 2.f), 0), 15);
    int qz = min(max((int)((p[2] + 4.f) * 2.f), 0), 15);
    auto ex = [](int v) {
      return (v & 1) | ((v & 2) << 2) | ((v & 4) << 4) | ((v & 8) << 6);
    };
    int code = ex(qx) | (ex(qy) << 1) | (ex(qz) << 2);
    codes[n] = (unsigned short)code;
    atomicAdd(&hist[code], 1u);
  }
  __syncthreads();

  unsigned int loc[16], s = 0;
#pragma unroll
  for (int j = 0; j < 16; ++j) { loc[j] = s; s += hist[tid * 16 + j]; }
  part[tid] = s;
  __syncthreads();
  if (tid == 0) {
    unsigned int run = 0;
    for (int t = 0; t < TPB; ++t) { unsigned int v = part[t]; part[t] = run; run += v; }
  }
  __syncthreads();
  {
    unsigned int base = part[tid];
#pragma unroll
    for (int j = 0; j < 16; ++j) hist[tid * 16 + j] = base + loc[j];
  }
  __syncthreads();

  for (int j = 0; j < NPTS / TPB; ++j) {
    int n = j * TPB + tid;
    const float* p = src + ((size_t)b * NPTS + n) * 3;
    unsigned int pos = atomicAdd(&hist[codes[n]], 1u);
    dst[(size_t)b * NPTS + pos] = make_float4(p[0], p[1], p[2], 0.f);
  }
  __syncthreads();   // drains vmem; sorted data visible to this block

  if (tid < 64) {    // granule tid: bbox over 64 sorted points
    float mnx = 1e30f, mny = 1e30f, mnz = 1e30f;
    float mxx = -1e30f, mxy = -1e30f, mxz = -1e30f;
    for (int j = 0; j < CHUNK; ++j) {
      float4 p = dst[(size_t)b * NPTS + tid * CHUNK + j];
      mnx = fminf(mnx, p.x); mxx = fmaxf(mxx, p.x);
      mny = fminf(mny, p.y); mxy = fmaxf(mxy, p.y);
      mnz = fminf(mnz, p.z); mxz = fmaxf(mxz, p.z);
    }
    size_t bi = ((size_t)(set * NB + b) * 64 + tid) * 2;
    bb[bi + 0] = make_float4(mnx, mny, mnz, 0.f);
    bb[bi + 1] = make_float4(mxx, mxy, mxz, 0.f);
  }
}

// ---------------------------------------------------------------------------
// CA kernel: C_i (rsum[n] += e_i*u[m], e_i = e_{i+1}^4) fused with A_{i+1}
// (denom[n] += e_{i+1}*rr[m]).  Atomic accumulation into dAcc/rAcc.
// MODE 0: A_0 only.  MODE 1: middle.  MODE 2: i=8 (level_{i+1}=0 -> +rr; e_8).
// CULL: wave-level bbox cull vs staged granule.  PSKIP: per-point group skip.
// ---------------------------------------------------------------------------
template<int MODE, bool CULL, bool PSKIP>
__global__ __launch_bounds__(TPB) void ca_kernel(
    const float4* __restrict__ x2p, const float4* __restrict__ x1p,
    const float2* __restrict__ urbuf,
    float* __restrict__ dAcc, float* __restrict__ rAcc,
    const float4* __restrict__ bb2,     // set-1 granule bboxes
    float sc)
{
  __shared__ float4 x2s[CHUNK];
  __shared__ float2 urs[CHUNK];

  const int tid = threadIdx.x;
  const int nchunk = blockIdx.x, mseg = blockIdx.y, b = blockIdx.z;

  for (int mm = tid; mm < CHUNK; mm += TPB) {
    int m = mseg * CHUNK + mm;
    float4 q = x2p[(size_t)b * NPTS + m];
    float sx = sc * q.x, sy = sc * q.y, sz = sc * q.z;
    float nq = fmaf(sz, sz, fmaf(sy, sy, sx * sx));
    x2s[mm] = make_float4(-2.f * sx, -2.f * sy, -2.f * sz, nq);
    urs[mm] = (MODE == 0) ? make_float2(0.f, 1.f)
                          : urbuf[(size_t)b * NPTS + m];
  }
  __syncthreads();

  const int n0 = nchunk * (TPB * MBLK) + tid * MBLK;
  float px[MBLK], py[MBLK], pz[MBLK], np[MBLK], dacc[MBLK], racc[MBLK];
#pragma unroll
  for (int k = 0; k < MBLK; ++k) {
    float4 p = x1p[(size_t)b * NPTS + n0 + k];
    px[k] = sc * p.x; py[k] = sc * p.y; pz[k] = sc * p.z;
    np[k] = fmaf(pz[k], pz[k], fmaf(py[k], py[k], px[k] * px[k]));
    dacc[k] = 0.f; racc[k] = 0.f;
  }

  if (CULL) {
    float mnx = fminf(fminf(px[0], px[1]), fminf(px[2], px[3]));
    float mny = fminf(fminf(py[0], py[1]), fminf(py[2], py[3]));
    float mnz = fminf(fminf(pz[0], pz[1]), fminf(pz[2], pz[3]));
    float mxx = fmaxf(fmaxf(px[0], px[1]), fmaxf(px[2], px[3]));
    float mxy = fmaxf(fmaxf(py[0], py[1]), fmaxf(py[2], py[3]));
    float mxz = fmaxf(fmaxf(pz[0], pz[1]), fmaxf(pz[2], pz[3]));
#pragma unroll
    for (int off = 1; off < 64; off <<= 1) {
      mnx = fminf(mnx, __shfl_xor(mnx, off));
      mny = fminf(mny, __shfl_xor(mny, off));
      mnz = fminf(mnz, __shfl_xor(mnz, off));
      mxx = fmaxf(mxx, __shfl_xor(mxx, off));
      mxy = fmaxf(mxy, __shfl_xor(mxy, off));
      mxz = fmaxf(mxz, __shfl_xor(mxz, off));
    }
    size_t bi = ((size_t)b * 64 + mseg) * 2;
    float4 smin = bb2[bi + 0], smax = bb2[bi + 1];
    float gx = fmaxf(0.f, fmaxf(sc * smin.x - mxx, mnx - sc * smax.x));
    float gy = fmaxf(0.f, fmaxf(sc * smin.y - mxy, mny - sc * smax.y));
    float gz = fmaxf(0.f, fmaxf(sc * smin.z - mxz, mnz - sc * smax.z));
    if (fmaf(gx, gx, fmaf(gy, gy, gz * gz)) >= 126.f) return;
  }

#pragma unroll 4
  for (int mm = 0; mm < CHUNK; ++mm) {
    float4 q = x2s[mm];
    float2 ur = urs[mm];
    float ds2[MBLK];
#pragma unroll
    for (int k = 0; k < MBLK; ++k)
      ds2[k] = fmaf(q.x, px[k], fmaf(q.y, py[k], fmaf(q.z, pz[k], np[k] + q.w)));
    if (MODE == 2) {
#pragma unroll
      for (int k = 0; k < MBLK; ++k) {
        dacc[k] += ur.y;
        racc[k] = fmaf(EXP2(-ds2[k]), ur.x, racc[k]);
      }
    } else {
      bool go = true;
      if (PSKIP) {
        float dmin = fminf(fminf(ds2[0], ds2[1]), fminf(ds2[2], ds2[3]));
        go = dmin < 126.f;
      }
      if (go) {
#pragma unroll
        for (int k = 0; k < MBLK; ++k) {
          float en = EXP2(-ds2[k]);
          dacc[k] = fmaf(en, ur.y, dacc[k]);
          if (MODE == 1) { float e2 = en * en; racc[k] = fmaf(e2 * e2, ur.x, racc[k]); }
        }
      }
    }
  }

  size_t off = (size_t)b * NPTS + n0;
#pragma unroll
  for (int k = 0; k < MBLK; ++k) {
    atomicAdd(&dAcc[off + k], dacc[k]);
    if (MODE >= 1) atomicAdd(&rAcc[off + k], racc[k]);
  }
}

// ---------------------------------------------------------------------------
// B kernel: s0[m] += sum_n a*e_i, s1[m] += sum_n a*e_i*dist (de-scaled once).
// LVL0: i=9 (e=1, sc=1).  Atomic accumulation into s0Acc/s1Acc.
// ---------------------------------------------------------------------------
template<int LVL0, bool CULL, bool PSKIP>
__global__ __launch_bounds__(TPB) void b_kernel(
    const float4* __restrict__ x1p, const float* __restrict__ abuf,
    const float4* __restrict__ x2p,
    float* __restrict__ s0Acc, float* __restrict__ s1Acc,
    const float4* __restrict__ bb1,     // set-0 granule bboxes
    float sc, float inv_s)
{
  __shared__ float4 x1s[CHUNK];
  __shared__ float  as_[CHUNK];

  const int tid = threadIdx.x;
  const int mchunk = blockIdx.x, nsegi = blockIdx.y, b = blockIdx.z;

  for (int nn = tid; nn < CHUNK; nn += TPB) {
    int n = nsegi * CHUNK + nn;
    float4 p = x1p[(size_t)b * NPTS + n];
    float sx = sc * p.x, sy = sc * p.y, sz = sc * p.z;
    float npv = fmaf(sz, sz, fmaf(sy, sy, sx * sx));
    x1s[nn] = make_float4(-2.f * sx, -2.f * sy, -2.f * sz, npv);
    as_[nn] = abuf[(size_t)b * NPTS + n];
  }
  __syncthreads();

  const int m0 = mchunk * (TPB * MBLK) + tid * MBLK;
  float qx[MBLK], qy[MBLK], qz[MBLK], nq[MBLK], s0a[MBLK], s1a[MBLK];
#pragma unroll
  for (int k = 0; k < MBLK; ++k) {
    float4 q = x2p[(size_t)b * NPTS + m0 + k];
    qx[k] = sc * q.x; qy[k] = sc * q.y; qz[k] = sc * q.z;
    nq[k] = fmaf(qz[k], qz[k], fmaf(qy[k], qy[k], qx[k] * qx[k]));
    s0a[k] = 0.f; s1a[k] = 0.f;
  }

  if (CULL) {
    float mnx = fminf(fminf(qx[0], qx[1]), fminf(qx[2], qx[3]));
    float mny = fminf(fminf(qy[0], qy[1]), fminf(qy[2], qy[3]));
    float mnz = fminf(fminf(qz[0], qz[1]), fminf(qz[2], qz[3]));
    float mxx = fmaxf(fmaxf(qx[0], qx[1]), fmaxf(qx[2], qx[3]));
    float mxy = fmaxf(fmaxf(qy[0], qy[1]), fmaxf(qy[2], qy[3]));
    float mxz = fmaxf(fmaxf(qz[0], qz[1]), fmaxf(qz[2], qz[3]));
#pragma unroll
    for (int off = 1; off < 64; off <<= 1) {
      mnx = fminf(mnx, __shfl_xor(mnx, off));
      mny = fminf(mny, __shfl_xor(mny, off));
      mnz = fminf(mnz, __shfl_xor(mnz, off));
      mxx = fmaxf(mxx, __shfl_xor(mxx, off));
      mxy = fmaxf(mxy, __shfl_xor(mxy, off));
      mxz = fmaxf(mxz, __shfl_xor(mxz, off));
    }
    size_t bi = ((size_t)b * 64 + nsegi) * 2;
    float4 smin = bb1[bi + 0], smax = bb1[bi + 1];
    float gx = fmaxf(0.f, fmaxf(sc * smin.x - mxx, mnx - sc * smax.x));
    float gy = fmaxf(0.f, fmaxf(sc * smin.y - mxy, mny - sc * smax.y));
    float gz = fmaxf(0.f, fmaxf(sc * smin.z - mxz, mnz - sc * smax.z));
    if (fmaf(gx, gx, fmaf(gy, gy, gz * gz)) >= 126.f) return;
  }

#pragma unroll 4
  for (int nn = 0; nn < CHUNK; ++nn) {
    float4 p = x1s[nn];
    float av = as_[nn];
    float ds2[MBLK];
#pragma unroll
    for (int k = 0; k < MBLK; ++k)
      ds2[k] = fmaf(p.x, qx[k], fmaf(p.y, qy[k], fmaf(p.z, qz[k], nq[k] + p.w)));
    if (LVL0) {
#pragma unroll
      for (int k = 0; k < MBLK; ++k) {
        s0a[k] += av;
        s1a[k] = fmaf(av, SQRTF(__builtin_fabsf(ds2[k])), s1a[k]);
      }
    } else {
      bool go = true;
      if (PSKIP) {
        float dmin = fminf(fminf(ds2[0], ds2[1]), fminf(ds2[2], ds2[3]));
        go = dmin < 126.f;
      }
      if (go) {
#pragma unroll
        for (int k = 0; k < MBLK; ++k) {
          float tt = av * EXP2(-ds2[k]);
          s0a[k] += tt;
          s1a[k] = fmaf(tt, SQRTF(__builtin_fabsf(ds2[k])), s1a[k]);
        }
      }
    }
  }

  size_t off = (size_t)b * NPTS + m0;
#pragma unroll
  for (int k = 0; k < MBLK; ++k) {
    atomicAdd(&s0Acc[off + k], s0a[k]);
    atomicAdd(&s1Acc[off + k], s1a[k] * inv_s);
  }
}

// ---------------------------------------------------------------------------
// R1 (before B_i): read denom_i (dAcc) / rsum_{i-1} (rAcc); remainL recurrence;
// a_i = rl/(denom+eps).  Zeroes s0Acc/s1Acc for B_i.
// ---------------------------------------------------------------------------
__global__ __launch_bounds__(TPBR) void r1_kernel(
    const float* __restrict__ dAcc, const float* __restrict__ rAcc,
    float* __restrict__ lbuf, float* __restrict__ dtot,
    float* __restrict__ abuf,
    float* __restrict__ s0Acc, float* __restrict__ s1Acc, int iter)
{
  const int idx = blockIdx.x * TPBR + threadIdx.x;
  float dnew = dAcc[idx];
  float rl = 1.f;
  if (iter > 0) {
    float rlp = lbuf[idx];
    float ap  = rlp * RCPF(dtot[idx] + EPSC);
    rl = fmaxf(rlp - ap * rAcc[idx], 0.f);
  }
  lbuf[idx] = rl;
  dtot[idx] = dnew;
  abuf[idx] = rl * RCPF(dnew + EPSC);
  s0Acc[idx] = 0.f;
  s1Acc[idx] = 0.f;
}

// ---------------------------------------------------------------------------
// R2 (after B_i): u_i, rr update (urbuf), cost partial -> out[b] (atomic).
// Zeroes dAcc/rAcc for CA_i.
// ---------------------------------------------------------------------------
template<bool LAST>
__global__ __launch_bounds__(TPBR) void r2_kernel(
    const float* __restrict__ s0Acc, const float* __restrict__ s1Acc,
    float2* __restrict__ urbuf,
    float* __restrict__ dAcc, float* __restrict__ rAcc,
    float* __restrict__ out, int iter)
{
  __shared__ float red[TPBR];
  const int idx = blockIdx.x * TPBR + threadIdx.x;
  const int b = idx >> 12;

  float s0 = s0Acc[idx], s1 = s1Acc[idx];
  float rr    = (iter == 0) ? 1.f : urbuf[idx].y;
  float sumr  = fmaf(rr, s0, EPSC);
  float ratio = fminf(rr * RCPF(sumr), 1.f);
  float u     = rr * ratio;
  if (!LAST) urbuf[idx] = make_float2(u, fmaxf(rr - u * s0, 0.f));
  dAcc[idx] = 0.f;
  rAcc[idx] = 0.f;

  red[threadIdx.x] = u * s1;
  __syncthreads();
  for (int s = TPBR / 2; s > 0; s >>= 1) {
    if (threadIdx.x < s) red[threadIdx.x] += red[threadIdx.x + s];
    __syncthreads();
  }
  if (threadIdx.x == 0) atomicAdd(out + b, red[0]);
}

extern "C" void kernel_launch(void* const* d_in, const int* in_sizes, int n_in,
                              void* d_out, int out_size, void* d_ws, size_t ws_size,
                              hipStream_t stream) {
  const float* x1 = (const float*)d_in[0];
  const float* x2 = (const float*)d_in[1];
  float* out = (float*)d_out;

  const size_t plane = (size_t)NB * NPTS;
  float*  ws    = (float*)d_ws;
  float*  dAcc  = ws;                    // 1 plane
  float*  rAcc  = dAcc + plane;          // 1 plane (contiguous with dAcc)
  float*  s0Acc = rAcc + plane;
  float*  s1Acc = s0Acc + plane;
  float*  dtot  = s1Acc + plane;
  float*  lbuf  = dtot + plane;
  float*  abuf  = lbuf + plane;
  float2* urbuf = (float2*)(abuf + plane);          // 2 planes
  float4* x1p   = (float4*)(urbuf + plane);         // 4 planes
  float4* x2p   = x1p + plane;                      // 4 planes
  float4* bb    = x2p + plane;                      // 2*8*64*2 float4 = 8 KB*4
  float4* bb1   = bb;                               // set 0
  float4* bb2   = bb + (size_t)NB * 64 * 2;         // set 1

  const double L2E = 1.4426950408889634074;
  const double lv[10] = {-16384.0, -4096.0, -1024.0, -256.0, -64.0,
                         -16.0, -4.0, -1.0, -0.25, 0.0};
  float scl[10], inv_s[10];
  for (int i = 0; i < 10; ++i) {
    double c2 = lv[i] * L2E;
    scl[i]   = (i == 9) ? 1.f : (float)sqrt(-c2);
    inv_s[i] = (i == 9) ? 1.f : (float)(1.0 / sqrt(-c2));
  }

  dim3 gmain(NPTS / (TPB * MBLK), NSEG, NB), bmain(TPB);
  dim3 gr(NB * NPTS / TPBR), br(TPBR);

  sort_kernel<<<dim3(2, NB), bmain, 0, stream>>>(x1, x2, x1p, x2p, bb, dAcc, out);

  // A_0: denom_0 partials (level -16384)
  ca_kernel<0, true, true><<<gmain, bmain, 0, stream>>>(
      x2p, x1p, urbuf, dAcc, rAcc, bb2, scl[0]);

  for (int i = 0; i < 10; ++i) {
    r1_kernel<<<gr, br, 0, stream>>>(dAcc, rAcc, lbuf, dtot, abuf,
                                     s0Acc, s1Acc, i);

    if (i <= 4)
      b_kernel<0, true, true><<<gmain, bmain, 0, stream>>>(
          x1p, abuf, x2p, s0Acc, s1Acc, bb1, scl[i], inv_s[i]);
    else if (i == 5)
      b_kernel<0, true, false><<<gmain, bmain, 0, stream>>>(
          x1p, abuf, x2p, s0Acc, s1Acc, bb1, scl[i], inv_s[i]);
    else if (i <= 8)
      b_kernel<0, false, false><<<gmain, bmain, 0, stream>>>(
          x1p, abuf, x2p, s0Acc, s1Acc, bb1, scl[i], inv_s[i]);
    else
      b_kernel<1, false, false><<<gmain, bmain, 0, stream>>>(
          x1p, abuf, x2p, s0Acc, s1Acc, bb1, 1.f, 1.f);

    if (i < 9)
      r2_kernel<false><<<gr, br, 0, stream>>>(s0Acc, s1Acc, urbuf,
                                              dAcc, rAcc, out, i);
    else
      r2_kernel<true><<<gr, br, 0, stream>>>(s0Acc, s1Acc, urbuf,
                                             dAcc, rAcc, out, i);

    if (i <= 3)
      ca_kernel<1, true, true><<<gmain, bmain, 0, stream>>>(
          x2p, x1p, urbuf, dAcc, rAcc, bb2, scl[i + 1]);
    else if (i == 4)
      ca_kernel<1, true, false><<<gmain, bmain, 0, stream>>>(
          x2p, x1p, urbuf, dAcc, rAcc, bb2, scl[i + 1]);
    else if (i <= 7)
      ca_kernel<1, false, false><<<gmain, bmain, 0, stream>>>(
          x2p, x1p, urbuf, dAcc, rAcc, bb2, scl[i + 1]);
    else if (i == 8)
      ca_kernel<2, false, false><<<gmain, bmain, 0, stream>>>(
          x2p, x1p, urbuf, dAcc, rAcc, bb2, scl[8]);
  }
}

// Round 8
// 1009.747 us; speedup vs baseline: 1.6346x; 1.6346x over previous
//
#include <hip/hip_runtime.h>

#define NPTS 4096
#define NB   8
#define TPB  256
#define TPBR 128
#define MBLK 4
#define EPSC 1e-9f

#define EXP2(x)  __builtin_amdgcn_exp2f(x)
#define RCPF(x)  __builtin_amdgcn_rcpf(x)
#define SQRTF(x) __builtin_amdgcn_sqrtf(x)

// ---------------------------------------------------------------------------
// Morton bucket sort (4 bits/axis, 4096 buckets) per (set, batch) + per-64-
// point granule bboxes. Any permutation is exactly correct (cost is a
// set-pairwise sum); sorting only improves cull coherence.
// ---------------------------------------------------------------------------
__global__ __launch_bounds__(TPB) void sort_kernel(
    const float* __restrict__ x1, const float* __restrict__ x2,
    float4* __restrict__ x1p, float4* __restrict__ x2p,
    float4* __restrict__ bb)            // [2][NB][64][2] (min,max)
{
  __shared__ unsigned int   hist[4096];
  __shared__ unsigned short codes[4096];
  __shared__ unsigned int   part[TPB];

  const int set = blockIdx.x, b = blockIdx.y;
  const float* src = set ? x2 : x1;
  float4* dst = set ? x2p : x1p;
  const int tid = threadIdx.x;

  for (int i = tid; i < 4096; i += TPB) hist[i] = 0;
  __syncthreads();

  for (int j = 0; j < NPTS / TPB; ++j) {
    int n = j * TPB + tid;
    const float* p = src + ((size_t)b * NPTS + n) * 3;
    int qx = min(max((int)((p[0] + 4.f) * 2.f), 0), 15);
    int qy = min(max((int)((p[1] + 4.f) * 2.f), 0), 15);
    int qz = min(max((int)((p[2] + 4.f) * 2.f), 0), 15);
    auto ex = [](int v) {
      return (v & 1) | ((v & 2) << 2) | ((v & 4) << 4) | ((v & 8) << 6);
    };
    int code = ex(qx) | (ex(qy) << 1) | (ex(qz) << 2);
    codes[n] = (unsigned short)code;
    atomicAdd(&hist[code], 1u);
  }
  __syncthreads();

  unsigned int loc[16], s = 0;
#pragma unroll
  for (int j = 0; j < 16; ++j) { loc[j] = s; s += hist[tid * 16 + j]; }
  part[tid] = s;
  __syncthreads();
  if (tid == 0) {
    unsigned int run = 0;
    for (int t = 0; t < TPB; ++t) { unsigned int v = part[t]; part[t] = run; run += v; }
  }
  __syncthreads();
  {
    unsigned int base = part[tid];
#pragma unroll
    for (int j = 0; j < 16; ++j) hist[tid * 16 + j] = base + loc[j];
  }
  __syncthreads();

  for (int j = 0; j < NPTS / TPB; ++j) {
    int n = j * TPB + tid;
    const float* p = src + ((size_t)b * NPTS + n) * 3;
    unsigned int pos = atomicAdd(&hist[codes[n]], 1u);
    dst[(size_t)b * NPTS + pos] = make_float4(p[0], p[1], p[2], 0.f);
  }
  __syncthreads();   // vmem drained at barrier; same-CU L1 -> coherent reads

  if (tid < 64) {    // bbox over this granule's 64 sorted points
    float mnx = 1e30f, mny = 1e30f, mnz = 1e30f;
    float mxx = -1e30f, mxy = -1e30f, mxz = -1e30f;
    for (int j = 0; j < 64; ++j) {
      float4 p = dst[(size_t)b * NPTS + tid * 64 + j];
      mnx = fminf(mnx, p.x); mxx = fmaxf(mxx, p.x);
      mny = fminf(mny, p.y); mxy = fmaxf(mxy, p.y);
      mnz = fminf(mnz, p.z); mxz = fmaxf(mxz, p.z);
    }
    size_t bi = ((size_t)(set * NB + b) * 64 + tid) * 2;
    bb[bi + 0] = make_float4(mnx, mny, mnz, 0.f);
    bb[bi + 1] = make_float4(mxx, mxy, mxz, 0.f);
  }
}

// wave bbox of MBLK-per-lane owned coords, then scaled gap^2 vs granule bbox
__device__ __forceinline__ bool wave_cull(
    const float px[MBLK], const float py[MBLK], const float pz[MBLK],
    const float4* bbg, size_t gi, float sc)
{
  float mnx = fminf(fminf(px[0], px[1]), fminf(px[2], px[3]));
  float mny = fminf(fminf(py[0], py[1]), fminf(py[2], py[3]));
  float mnz = fminf(fminf(pz[0], pz[1]), fminf(pz[2], pz[3]));
  float mxx = fmaxf(fmaxf(px[0], px[1]), fmaxf(px[2], px[3]));
  float mxy = fmaxf(fmaxf(py[0], py[1]), fmaxf(py[2], py[3]));
  float mxz = fmaxf(fmaxf(pz[0], pz[1]), fmaxf(pz[2], pz[3]));
#pragma unroll
  for (int off = 1; off < 64; off <<= 1) {
    mnx = fminf(mnx, __shfl_xor(mnx, off));
    mny = fminf(mny, __shfl_xor(mny, off));
    mnz = fminf(mnz, __shfl_xor(mnz, off));
    mxx = fmaxf(mxx, __shfl_xor(mxx, off));
    mxy = fmaxf(mxy, __shfl_xor(mxy, off));
    mxz = fmaxf(mxz, __shfl_xor(mxz, off));
  }
  float4 smin = bbg[gi * 2 + 0], smax = bbg[gi * 2 + 1];
  float gx = fmaxf(0.f, fmaxf(sc * smin.x - mxx, mnx - sc * smax.x));
  float gy = fmaxf(0.f, fmaxf(sc * smin.y - mxy, mny - sc * smax.y));
  float gz = fmaxf(0.f, fmaxf(sc * smin.z - mxz, mnz - sc * smax.z));
  return fmaf(gx, gx, fmaf(gy, gy, gz * gz)) >= 126.f;
}

// ---------------------------------------------------------------------------
// CA kernel: C_i (rsum[n] = sum_m e_i*u[m], e_i = e_{i+1}^4) fused with
// A_{i+1} (denom[n] = sum_m e_{i+1}*rr[m]).  Dot-product form, partial-plane
// stores.  MODE 0: A_0 only (zeroes out).  MODE 2: i=8 (denom += rr; e_8).
// CULL: per-wave bbox cull -> zero-fill + return (after the single barrier).
// ---------------------------------------------------------------------------
template<int MODE, bool CULL, bool PSKIP, int CHUNK>
__global__ __launch_bounds__(TPB) void ca_kernel(
    const float4* __restrict__ x2p, const float4* __restrict__ x1p,
    const float2* __restrict__ urbuf,
    float* __restrict__ dbufP, float* __restrict__ rsumP,
    const float4* __restrict__ bb2, float* __restrict__ out, float sc)
{
  __shared__ float4 x2s[CHUNK];
  __shared__ float2 urs[CHUNK];

  const int tid = threadIdx.x;
  const int nchunk = blockIdx.x, mseg = blockIdx.y, b = blockIdx.z;

  if (MODE == 0 && nchunk == 0 && mseg == 0 && tid == 0) out[b] = 0.f;

  for (int mm = tid; mm < CHUNK; mm += TPB) {
    int m = mseg * CHUNK + mm;
    float4 q = x2p[(size_t)b * NPTS + m];
    float sx = sc * q.x, sy = sc * q.y, sz = sc * q.z;
    float nq = fmaf(sz, sz, fmaf(sy, sy, sx * sx));
    x2s[mm] = make_float4(-2.f * sx, -2.f * sy, -2.f * sz, nq);
    urs[mm] = (MODE == 0) ? make_float2(0.f, 1.f) : urbuf[(size_t)b * NPTS + m];
  }
  __syncthreads();

  const int n0 = nchunk * (TPB * MBLK) + tid * MBLK;
  float px[MBLK], py[MBLK], pz[MBLK], np[MBLK], dacc[MBLK], racc[MBLK];
#pragma unroll
  for (int k = 0; k < MBLK; ++k) {
    float4 p = x1p[(size_t)b * NPTS + n0 + k];
    px[k] = sc * p.x; py[k] = sc * p.y; pz[k] = sc * p.z;
    np[k] = fmaf(pz[k], pz[k], fmaf(py[k], py[k], px[k] * px[k]));
    dacc[k] = 0.f; racc[k] = 0.f;
  }

  size_t base = ((size_t)mseg * NB + b) * NPTS + n0;
  if (CULL) {
    if (wave_cull(px, py, pz, bb2 + (size_t)b * 128, mseg, sc)) {
      *(float4*)&dbufP[base] = make_float4(0.f, 0.f, 0.f, 0.f);
      if (MODE >= 1) *(float4*)&rsumP[base] = make_float4(0.f, 0.f, 0.f, 0.f);
      return;
    }
  }

#pragma unroll 4
  for (int mm = 0; mm < CHUNK; ++mm) {
    float4 q = x2s[mm];
    float2 ur = urs[mm];
    float ds2[MBLK];
#pragma unroll
    for (int k = 0; k < MBLK; ++k)
      ds2[k] = fmaf(q.x, px[k], fmaf(q.y, py[k], fmaf(q.z, pz[k], np[k] + q.w)));
    if (MODE == 2) {
#pragma unroll
      for (int k = 0; k < MBLK; ++k) {
        dacc[k] += ur.y;
        racc[k] = fmaf(EXP2(-ds2[k]), ur.x, racc[k]);
      }
    } else {
      bool go = true;
      if (PSKIP) {
        float dmin = fminf(fminf(ds2[0], ds2[1]), fminf(ds2[2], ds2[3]));
        go = dmin < 126.f;
      }
      if (go) {
#pragma unroll
        for (int k = 0; k < MBLK; ++k) {
          float en = EXP2(-ds2[k]);
          dacc[k] = fmaf(en, ur.y, dacc[k]);
          if (MODE == 1) { float e2 = en * en; racc[k] = fmaf(e2 * e2, ur.x, racc[k]); }
        }
      }
    }
  }

  *(float4*)&dbufP[base] = make_float4(dacc[0], dacc[1], dacc[2], dacc[3]);
  if (MODE >= 1)
    *(float4*)&rsumP[base] = make_float4(racc[0], racc[1], racc[2], racc[3]);
}

// ---------------------------------------------------------------------------
// B kernel: s0[m] = sum_n a*e_i, s1[m] = sum_n a*e_i*dist (de-scaled once).
// LVL0: i=9 (e=1, sc=1).  Partial-plane stores + wave cull.
// ---------------------------------------------------------------------------
template<int LVL0, bool CULL, bool PSKIP, int CHUNK>
__global__ __launch_bounds__(TPB) void b_kernel(
    const float4* __restrict__ x1p, const float* __restrict__ abuf,
    const float4* __restrict__ x2p,
    float* __restrict__ s0P, float* __restrict__ s1P,
    const float4* __restrict__ bb1, float sc, float inv_s)
{
  __shared__ float4 x1s[CHUNK];
  __shared__ float  as_[CHUNK];

  const int tid = threadIdx.x;
  const int mchunk = blockIdx.x, nsegi = blockIdx.y, b = blockIdx.z;

  for (int nn = tid; nn < CHUNK; nn += TPB) {
    int n = nsegi * CHUNK + nn;
    float4 p = x1p[(size_t)b * NPTS + n];
    float sx = sc * p.x, sy = sc * p.y, sz = sc * p.z;
    float npv = fmaf(sz, sz, fmaf(sy, sy, sx * sx));
    x1s[nn] = make_float4(-2.f * sx, -2.f * sy, -2.f * sz, npv);
    as_[nn] = abuf[(size_t)b * NPTS + n];
  }
  __syncthreads();

  const int m0 = mchunk * (TPB * MBLK) + tid * MBLK;
  float qx[MBLK], qy[MBLK], qz[MBLK], nq[MBLK], s0a[MBLK], s1a[MBLK];
#pragma unroll
  for (int k = 0; k < MBLK; ++k) {
    float4 q = x2p[(size_t)b * NPTS + m0 + k];
    qx[k] = sc * q.x; qy[k] = sc * q.y; qz[k] = sc * q.z;
    nq[k] = fmaf(qz[k], qz[k], fmaf(qy[k], qy[k], qx[k] * qx[k]));
    s0a[k] = 0.f; s1a[k] = 0.f;
  }

  size_t base = ((size_t)nsegi * NB + b) * NPTS + m0;
  if (CULL) {
    if (wave_cull(qx, qy, qz, bb1 + (size_t)b * 128, nsegi, sc)) {
      *(float4*)&s0P[base] = make_float4(0.f, 0.f, 0.f, 0.f);
      *(float4*)&s1P[base] = make_float4(0.f, 0.f, 0.f, 0.f);
      return;
    }
  }

#pragma unroll 4
  for (int nn = 0; nn < CHUNK; ++nn) {
    float4 p = x1s[nn];
    float av = as_[nn];
    float ds2[MBLK];
#pragma unroll
    for (int k = 0; k < MBLK; ++k)
      ds2[k] = fmaf(p.x, qx[k], fmaf(p.y, qy[k], fmaf(p.z, qz[k], nq[k] + p.w)));
    if (LVL0) {
#pragma unroll
      for (int k = 0; k < MBLK; ++k) {
        s0a[k] += av;
        s1a[k] = fmaf(av, SQRTF(__builtin_fabsf(ds2[k])), s1a[k]);
      }
    } else {
      bool go = true;
      if (PSKIP) {
        float dmin = fminf(fminf(ds2[0], ds2[1]), fminf(ds2[2], ds2[3]));
        go = dmin < 126.f;
      }
      if (go) {
#pragma unroll
        for (int k = 0; k < MBLK; ++k) {
          float tt = av * EXP2(-ds2[k]);
          s0a[k] += tt;
          s1a[k] = fmaf(tt, SQRTF(__builtin_fabsf(ds2[k])), s1a[k]);
        }
      }
    }
  }

  *(float4*)&s0P[base] = make_float4(s0a[0], s0a[1], s0a[2], s0a[3]);
  *(float4*)&s1P[base] = make_float4(s1a[0] * inv_s, s1a[1] * inv_s,
                                     s1a[2] * inv_s, s1a[3] * inv_s);
}

// ---------------------------------------------------------------------------
// R1: n-side fixup. denom_i = sum dbufP; rl_i recurrence; a_i = rl/(denom+eps).
// ---------------------------------------------------------------------------
template<int NSEG>
__global__ __launch_bounds__(TPBR) void r1_kernel(
    const float* __restrict__ dbufP, const float* __restrict__ rsumP,
    float* __restrict__ lbuf, float* __restrict__ dtot,
    float* __restrict__ abuf, int iter)
{
  const int idx = blockIdx.x * TPBR + threadIdx.x;
  const int b = idx >> 12, n = idx & (NPTS - 1);
  const int off = b * NPTS + n;

  float dnew = 0.f;
#pragma unroll
  for (int s = 0; s < NSEG; ++s) dnew += dbufP[((size_t)s * NB + b) * NPTS + n];

  float rl;
  if (iter == 0) {
    rl = 1.f;
  } else {
    float rlp = lbuf[off];
    float ap  = rlp * RCPF(dtot[off] + EPSC);
    float rs = 0.f;
#pragma unroll
    for (int s = 0; s < NSEG; ++s) rs += rsumP[((size_t)s * NB + b) * NPTS + n];
    rl = fmaxf(rlp - ap * rs, 0.f);
  }
  lbuf[off] = rl;
  dtot[off] = dnew;
  abuf[off] = rl * RCPF(dnew + EPSC);
}

// ---------------------------------------------------------------------------
// R2: m-side fixup. s0 = sum s0P; u = rr*min(rr/(rr*s0+eps),1); rr update in
// place (urbuf = (u, rr)); cost partial atomically into out[b].
// ---------------------------------------------------------------------------
template<int NSEG, bool LAST>
__global__ __launch_bounds__(TPBR) void r2_kernel(
    const float* __restrict__ s0P, const float* __restrict__ s1P,
    float2* __restrict__ urbuf, float* __restrict__ out, int iter)
{
  __shared__ float red[TPBR];
  const int idx = blockIdx.x * TPBR + threadIdx.x;
  const int b = idx >> 12, m = idx & (NPTS - 1);
  const int off = b * NPTS + m;

  float s0 = 0.f, s1 = 0.f;
#pragma unroll
  for (int s = 0; s < NSEG; ++s) {
    s0 += s0P[((size_t)s * NB + b) * NPTS + m];
    s1 += s1P[((size_t)s * NB + b) * NPTS + m];
  }
  float rr    = (iter == 0) ? 1.f : urbuf[off].y;
  float sumr  = fmaf(rr, s0, EPSC);
  float ratio = fminf(rr * RCPF(sumr), 1.f);
  float u     = rr * ratio;
  if (!LAST) urbuf[off] = make_float2(u, fmaxf(rr - u * s0, 0.f));

  red[threadIdx.x] = u * s1;
  __syncthreads();
  for (int s = TPBR / 2; s > 0; s >>= 1) {
    if (threadIdx.x < s) red[threadIdx.x] += red[threadIdx.x + s];
    __syncthreads();
  }
  if (threadIdx.x == 0) atomicAdd(out + b, red[0]);
}

// ---------------------------------------------------------------------------
template<int NSEG>
static void run_all(const float* x1, const float* x2, float* out, float* ws,
                    hipStream_t stream)
{
  constexpr int CHUNK = NPTS / NSEG;
  const size_t plane = (size_t)NB * NPTS;

  float*  bufA = ws;                                      // NSEG planes
  float*  bufB = bufA + (size_t)NSEG * plane;             // NSEG planes
  float4* x1p  = (float4*)(bufB + (size_t)NSEG * plane);  // 4 planes
  float4* x2p  = x1p + plane;                             // 4 planes
  float*  dtot = (float*)(x2p + plane);
  float*  lbuf = dtot + plane;
  float*  abuf = lbuf + plane;
  float2* urbuf = (float2*)(abuf + plane);                // 2 planes
  float4* bb   = (float4*)(urbuf + plane);                // 2048 float4
  float4* bb1  = bb;
  float4* bb2  = bb + (size_t)NB * 128;

  const double L2E = 1.4426950408889634074;
  const double lv[10] = {-16384.0, -4096.0, -1024.0, -256.0, -64.0,
                         -16.0, -4.0, -1.0, -0.25, 0.0};
  float scl[10], inv_s[10];
  for (int i = 0; i < 10; ++i) {
    double c2 = lv[i] * L2E;
    scl[i]   = (i == 9) ? 1.f : (float)sqrt(-c2);
    inv_s[i] = (i == 9) ? 1.f : (float)(1.0 / sqrt(-c2));
  }

  dim3 gmain(NPTS / (TPB * MBLK), NSEG, NB), bmain(TPB);
  dim3 gr(NPTS * NB / TPBR), br(TPBR);

  sort_kernel<<<dim3(2, NB), bmain, 0, stream>>>(x1, x2, x1p, x2p, bb);

  // A_0: denom_0 partials (level -16384), zero out[]
  ca_kernel<0, true, true, CHUNK><<<gmain, bmain, 0, stream>>>(
      x2p, x1p, urbuf, bufA, bufB, bb2, out, scl[0]);

  for (int i = 0; i < 10; ++i) {
    r1_kernel<NSEG><<<gr, br, 0, stream>>>(bufA, bufB, lbuf, dtot, abuf, i);

    if (i <= 4)
      b_kernel<0, true, true, CHUNK><<<gmain, bmain, 0, stream>>>(
          x1p, abuf, x2p, bufA, bufB, bb1, scl[i], inv_s[i]);
    else if (i == 5)
      b_kernel<0, true, false, CHUNK><<<gmain, bmain, 0, stream>>>(
          x1p, abuf, x2p, bufA, bufB, bb1, scl[i], inv_s[i]);
    else if (i <= 8)
      b_kernel<0, false, false, CHUNK><<<gmain, bmain, 0, stream>>>(
          x1p, abuf, x2p, bufA, bufB, bb1, scl[i], inv_s[i]);
    else
      b_kernel<1, false, false, CHUNK><<<gmain, bmain, 0, stream>>>(
          x1p, abuf, x2p, bufA, bufB, bb1, 1.f, 1.f);

    if (i < 9)
      r2_kernel<NSEG, false><<<gr, br, 0, stream>>>(bufA, bufB, urbuf, out, i);
    else
      r2_kernel<NSEG, true><<<gr, br, 0, stream>>>(bufA, bufB, urbuf, out, i);

    if (i <= 3)
      ca_kernel<1, true, true, CHUNK><<<gmain, bmain, 0, stream>>>(
          x2p, x1p, urbuf, bufA, bufB, bb2, out, scl[i + 1]);
    else if (i <= 5)
      ca_kernel<1, true, false, CHUNK><<<gmain, bmain, 0, stream>>>(
          x2p, x1p, urbuf, bufA, bufB, bb2, out, scl[i + 1]);
    else if (i <= 7)
      ca_kernel<1, false, false, CHUNK><<<gmain, bmain, 0, stream>>>(
          x2p, x1p, urbuf, bufA, bufB, bb2, out, scl[i + 1]);
    else if (i == 8)
      ca_kernel<2, false, false, CHUNK><<<gmain, bmain, 0, stream>>>(
          x2p, x1p, urbuf, bufA, bufB, bb2, out, scl[8]);
  }
}

extern "C" void kernel_launch(void* const* d_in, const int* in_sizes, int n_in,
                              void* d_out, int out_size, void* d_ws, size_t ws_size,
                              hipStream_t stream) {
  const float* x1 = (const float*)d_in[0];
  const float* x2 = (const float*)d_in[1];
  float* out = (float*)d_out;
  float* ws  = (float*)d_ws;

  const size_t plane = (size_t)NB * NPTS;
  auto need = [&](int nseg) {
    return (size_t)(2 * nseg + 13) * plane * sizeof(float)
         + (size_t)2048 * sizeof(float4);
  };

  if (ws_size >= need(64))      run_all<64>(x1, x2, out, ws, stream);
  else if (ws_size >= need(32)) run_all<32>(x1, x2, out, ws, stream);
  else                          run_all<16>(x1, x2, out, ws, stream);
}

// Round 11
// 987.729 us; speedup vs baseline: 1.6710x; 1.0223x over previous
//
#include <hip/hip_runtime.h>

#define NPTS 4096
#define NB   8
#define TPB  256
#define MBLK 4
#define EPSC 1e-9f

#define EXP2(x)  __builtin_amdgcn_exp2f(x)
#define RCPF(x)  __builtin_amdgcn_rcpf(x)
#define SQRTF(x) __builtin_amdgcn_sqrtf(x)

// ---------------------------------------------------------------------------
// Morton bucket sort (4 bits/axis, 4096 buckets) per (set, batch) + per-64-
// point granule bboxes. Any permutation is exactly correct (cost is a
// set-pairwise sum); sorting only improves cull coherence.
// ---------------------------------------------------------------------------
__global__ __launch_bounds__(TPB) void sort_kernel(
    const float* __restrict__ x1, const float* __restrict__ x2,
    float4* __restrict__ x1p, float4* __restrict__ x2p,
    float4* __restrict__ bb)            // [2][NB][64][2] (min,max)
{
  __shared__ unsigned int   hist[4096];
  __shared__ unsigned short codes[4096];
  __shared__ unsigned int   part[TPB];

  const int set = blockIdx.x, b = blockIdx.y;
  const float* src = set ? x2 : x1;
  float4* dst = set ? x2p : x1p;
  const int tid = threadIdx.x;

  for (int i = tid; i < 4096; i += TPB) hist[i] = 0;
  __syncthreads();

  for (int j = 0; j < NPTS / TPB; ++j) {
    int n = j * TPB + tid;
    const float* p = src + ((size_t)b * NPTS + n) * 3;
    int qx = min(max((int)((p[0] + 4.f) * 2.f), 0), 15);
    int qy = min(max((int)((p[1] + 4.f) * 2.f), 0), 15);
    int qz = min(max((int)((p[2] + 4.f) * 2.f), 0), 15);
    auto ex = [](int v) {
      return (v & 1) | ((v & 2) << 2) | ((v & 4) << 4) | ((v & 8) << 6);
    };
    int code = ex(qx) | (ex(qy) << 1) | (ex(qz) << 2);
    codes[n] = (unsigned short)code;
    atomicAdd(&hist[code], 1u);
  }
  __syncthreads();

  unsigned int loc[16], s = 0;
#pragma unroll
  for (int j = 0; j < 16; ++j) { loc[j] = s; s += hist[tid * 16 + j]; }
  part[tid] = s;
  __syncthreads();
  if (tid == 0) {
    unsigned int run = 0;
    for (int t = 0; t < TPB; ++t) { unsigned int v = part[t]; part[t] = run; run += v; }
  }
  __syncthreads();
  {
    unsigned int base = part[tid];
#pragma unroll
    for (int j = 0; j < 16; ++j) hist[tid * 16 + j] = base + loc[j];
  }
  __syncthreads();

  for (int j = 0; j < NPTS / TPB; ++j) {
    int n = j * TPB + tid;
    const float* p = src + ((size_t)b * NPTS + n) * 3;
    unsigned int pos = atomicAdd(&hist[codes[n]], 1u);
    dst[(size_t)b * NPTS + pos] = make_float4(p[0], p[1], p[2], 0.f);
  }
  __syncthreads();   // vmem drained at barrier; same-CU L1 -> coherent reads

  if (tid < 64) {    // bbox over this granule's 64 sorted points
    float mnx = 1e30f, mny = 1e30f, mnz = 1e30f;
    float mxx = -1e30f, mxy = -1e30f, mxz = -1e30f;
    for (int j = 0; j < 64; ++j) {
      float4 p = dst[(size_t)b * NPTS + tid * 64 + j];
      mnx = fminf(mnx, p.x); mxx = fmaxf(mxx, p.x);
      mny = fminf(mny, p.y); mxy = fmaxf(mxy, p.y);
      mnz = fminf(mnz, p.z); mxz = fmaxf(mxz, p.z);
    }
    size_t bi = ((size_t)(set * NB + b) * 64 + tid) * 2;
    bb[bi + 0] = make_float4(mnx, mny, mnz, 0.f);
    bb[bi + 1] = make_float4(mxx, mxy, mxz, 0.f);
  }
}

// wave bbox of MBLK-per-lane owned coords, then scaled gap^2 vs granule bbox
__device__ __forceinline__ bool wave_cull(
    const float px[MBLK], const float py[MBLK], const float pz[MBLK],
    const float4* bbg, size_t gi, float sc)
{
  float mnx = fminf(fminf(px[0], px[1]), fminf(px[2], px[3]));
  float mny = fminf(fminf(py[0], py[1]), fminf(py[2], py[3]));
  float mnz = fminf(fminf(pz[0], pz[1]), fminf(pz[2], pz[3]));
  float mxx = fmaxf(fmaxf(px[0], px[1]), fmaxf(px[2], px[3]));
  float mxy = fmaxf(fmaxf(py[0], py[1]), fmaxf(py[2], py[3]));
  float mxz = fmaxf(fmaxf(pz[0], pz[1]), fmaxf(pz[2], pz[3]));
#pragma unroll
  for (int off = 1; off < 64; off <<= 1) {
    mnx = fminf(mnx, __shfl_xor(mnx, off));
    mny = fminf(mny, __shfl_xor(mny, off));
    mnz = fminf(mnz, __shfl_xor(mnz, off));
    mxx = fmaxf(mxx, __shfl_xor(mxx, off));
    mxy = fmaxf(mxy, __shfl_xor(mxy, off));
    mxz = fmaxf(mxz, __shfl_xor(mxz, off));
  }
  float4 smin = bbg[gi * 2 + 0], smax = bbg[gi * 2 + 1];
  float gx = fmaxf(0.f, fmaxf(sc * smin.x - mxx, mnx - sc * smax.x));
  float gy = fmaxf(0.f, fmaxf(sc * smin.y - mxy, mny - sc * smax.y));
  float gz = fmaxf(0.f, fmaxf(sc * smin.z - mxz, mnz - sc * smax.z));
  return fmaf(gx, gx, fmaf(gy, gy, gz * gz)) >= 126.f;
}

// ---------------------------------------------------------------------------
// CA kernel: C_i (rsum[n] = sum_m e_i*u[m], e_i = e_{i+1}^4) fused with
// A_{i+1} (denom[n] = sum_m e_{i+1}*rr[m]).  Dot-product form, partial-plane
// stores.  MODE 0: A_0 only (zeroes out).  MODE 2: i=8 (denom += rr; e_8).
// CULL: per-wave bbox cull -> zero-fill + return (after the single barrier).
// ---------------------------------------------------------------------------
template<int MODE, bool CULL, bool PSKIP, int CHUNK>
__global__ __launch_bounds__(TPB) void ca_kernel(
    const float4* __restrict__ x2p, const float4* __restrict__ x1p,
    const float2* __restrict__ urbuf,
    float* __restrict__ dbufP, float* __restrict__ rsumP,
    const float4* __restrict__ bb2, float* __restrict__ out, float sc)
{
  __shared__ float4 x2s[CHUNK];
  __shared__ float2 urs[CHUNK];

  const int tid = threadIdx.x;
  const int nchunk = blockIdx.x, mseg = blockIdx.y, b = blockIdx.z;

  if (MODE == 0 && nchunk == 0 && mseg == 0 && tid == 0) out[b] = 0.f;

  for (int mm = tid; mm < CHUNK; mm += TPB) {
    int m = mseg * CHUNK + mm;
    float4 q = x2p[(size_t)b * NPTS + m];
    float sx = sc * q.x, sy = sc * q.y, sz = sc * q.z;
    float nq = fmaf(sz, sz, fmaf(sy, sy, sx * sx));
    x2s[mm] = make_float4(-2.f * sx, -2.f * sy, -2.f * sz, nq);
    urs[mm] = (MODE == 0) ? make_float2(0.f, 1.f) : urbuf[(size_t)b * NPTS + m];
  }
  __syncthreads();

  const int n0 = nchunk * (TPB * MBLK) + tid * MBLK;
  float px[MBLK], py[MBLK], pz[MBLK], np[MBLK], dacc[MBLK], racc[MBLK];
#pragma unroll
  for (int k = 0; k < MBLK; ++k) {
    float4 p = x1p[(size_t)b * NPTS + n0 + k];
    px[k] = sc * p.x; py[k] = sc * p.y; pz[k] = sc * p.z;
    np[k] = fmaf(pz[k], pz[k], fmaf(py[k], py[k], px[k] * px[k]));
    dacc[k] = 0.f; racc[k] = 0.f;
  }

  size_t base = ((size_t)mseg * NB + b) * NPTS + n0;
  if (CULL) {
    if (wave_cull(px, py, pz, bb2 + (size_t)b * 128, mseg, sc)) {
      *(float4*)&dbufP[base] = make_float4(0.f, 0.f, 0.f, 0.f);
      if (MODE >= 1) *(float4*)&rsumP[base] = make_float4(0.f, 0.f, 0.f, 0.f);
      return;
    }
  }

#pragma unroll 4
  for (int mm = 0; mm < CHUNK; ++mm) {
    float4 q = x2s[mm];
    float2 ur = urs[mm];
    float ds2[MBLK];
#pragma unroll
    for (int k = 0; k < MBLK; ++k)
      ds2[k] = fmaf(q.x, px[k], fmaf(q.y, py[k], fmaf(q.z, pz[k], np[k] + q.w)));
    if (MODE == 2) {
#pragma unroll
      for (int k = 0; k < MBLK; ++k) {
        dacc[k] += ur.y;
        racc[k] = fmaf(EXP2(-ds2[k]), ur.x, racc[k]);
      }
    } else {
      bool go = true;
      if (PSKIP) {
        float dmin = fminf(fminf(ds2[0], ds2[1]), fminf(ds2[2], ds2[3]));
        go = dmin < 126.f;
      }
      if (go) {
#pragma unroll
        for (int k = 0; k < MBLK; ++k) {
          float en = EXP2(-ds2[k]);
          dacc[k] = fmaf(en, ur.y, dacc[k]);
          if (MODE == 1) { float e2 = en * en; racc[k] = fmaf(e2 * e2, ur.x, racc[k]); }
        }
      }
    }
  }

  *(float4*)&dbufP[base] = make_float4(dacc[0], dacc[1], dacc[2], dacc[3]);
  if (MODE >= 1)
    *(float4*)&rsumP[base] = make_float4(racc[0], racc[1], racc[2], racc[3]);
}

// ---------------------------------------------------------------------------
// B kernel: s0[m] = sum_n a*e_i, s1[m] = sum_n a*e_i*dist (de-scaled once).
// LVL0: i=9 (e=1, sc=1).  Partial-plane stores + wave cull.
// ---------------------------------------------------------------------------
template<int LVL0, bool CULL, bool PSKIP, int CHUNK>
__global__ __launch_bounds__(TPB) void b_kernel(
    const float4* __restrict__ x1p, const float* __restrict__ abuf,
    const float4* __restrict__ x2p,
    float* __restrict__ s0P, float* __restrict__ s1P,
    const float4* __restrict__ bb1, float sc, float inv_s)
{
  __shared__ float4 x1s[CHUNK];
  __shared__ float  as_[CHUNK];

  const int tid = threadIdx.x;
  const int mchunk = blockIdx.x, nsegi = blockIdx.y, b = blockIdx.z;

  for (int nn = tid; nn < CHUNK; nn += TPB) {
    int n = nsegi * CHUNK + nn;
    float4 p = x1p[(size_t)b * NPTS + n];
    float sx = sc * p.x, sy = sc * p.y, sz = sc * p.z;
    float npv = fmaf(sz, sz, fmaf(sy, sy, sx * sx));
    x1s[nn] = make_float4(-2.f * sx, -2.f * sy, -2.f * sz, npv);
    as_[nn] = abuf[(size_t)b * NPTS + n];
  }
  __syncthreads();

  const int m0 = mchunk * (TPB * MBLK) + tid * MBLK;
  float qx[MBLK], qy[MBLK], qz[MBLK], nq[MBLK], s0a[MBLK], s1a[MBLK];
#pragma unroll
  for (int k = 0; k < MBLK; ++k) {
    float4 q = x2p[(size_t)b * NPTS + m0 + k];
    qx[k] = sc * q.x; qy[k] = sc * q.y; qz[k] = sc * q.z;
    nq[k] = fmaf(qz[k], qz[k], fmaf(qy[k], qy[k], qx[k] * qx[k]));
    s0a[k] = 0.f; s1a[k] = 0.f;
  }

  size_t base = ((size_t)nsegi * NB + b) * NPTS + m0;
  if (CULL) {
    if (wave_cull(qx, qy, qz, bb1 + (size_t)b * 128, nsegi, sc)) {
      *(float4*)&s0P[base] = make_float4(0.f, 0.f, 0.f, 0.f);
      *(float4*)&s1P[base] = make_float4(0.f, 0.f, 0.f, 0.f);
      return;
    }
  }

#pragma unroll 4
  for (int nn = 0; nn < CHUNK; ++nn) {
    float4 p = x1s[nn];
    float av = as_[nn];
    float ds2[MBLK];
#pragma unroll
    for (int k = 0; k < MBLK; ++k)
      ds2[k] = fmaf(p.x, qx[k], fmaf(p.y, qy[k], fmaf(p.z, qz[k], nq[k] + p.w)));
    if (LVL0) {
#pragma unroll
      for (int k = 0; k < MBLK; ++k) {
        s0a[k] += av;
        s1a[k] = fmaf(av, SQRTF(__builtin_fabsf(ds2[k])), s1a[k]);
      }
    } else {
      bool go = true;
      if (PSKIP) {
        float dmin = fminf(fminf(ds2[0], ds2[1]), fminf(ds2[2], ds2[3]));
        go = dmin < 126.f;
      }
      if (go) {
#pragma unroll
        for (int k = 0; k < MBLK; ++k) {
          float tt = av * EXP2(-ds2[k]);
          s0a[k] += tt;
          s1a[k] = fmaf(tt, SQRTF(__builtin_fabsf(ds2[k])), s1a[k]);
        }
      }
    }
  }

  *(float4*)&s0P[base] = make_float4(s0a[0], s0a[1], s0a[2], s0a[3]);
  *(float4*)&s1P[base] = make_float4(s1a[0] * inv_s, s1a[1] * inv_s,
                                     s1a[2] * inv_s, s1a[3] * inv_s);
}

// ---------------------------------------------------------------------------
// R1 (wide): block = 32 elements x 8 seg-slices (256 thr). Each thread sums
// NSEG/8 planes (coalesced), LDS-combine, slice 0 does the remainL recurrence
// and a_i = rl/(denom+eps).  Grid 1024 blocks = 4096 waves (4/SIMD).
// ---------------------------------------------------------------------------
template<int NSEG>
__global__ __launch_bounds__(256) void r1_kernel(
    const float* __restrict__ dbufP, const float* __restrict__ rsumP,
    float* __restrict__ lbuf, float* __restrict__ dtot,
    float* __restrict__ abuf, int iter)
{
  constexpr int SL = 8, EPB = 32, PPS = NSEG / SL;
  __shared__ float redD[SL][EPB];
  __shared__ float redR[SL][EPB];

  const int e  = threadIdx.x & (EPB - 1);
  const int sl = threadIdx.x / EPB;
  const int idx = blockIdx.x * EPB + e;
  const size_t plane = (size_t)NB * NPTS;

  float ad = 0.f, ar = 0.f;
#pragma unroll
  for (int s = 0; s < PPS; ++s)
    ad += dbufP[(size_t)(sl * PPS + s) * plane + idx];
  if (iter > 0) {
#pragma unroll
    for (int s = 0; s < PPS; ++s)
      ar += rsumP[(size_t)(sl * PPS + s) * plane + idx];
  }
  redD[sl][e] = ad;
  redR[sl][e] = ar;
  __syncthreads();

  if (sl == 0) {
    float dnew = 0.f, rs = 0.f;
#pragma unroll
    for (int s = 0; s < SL; ++s) { dnew += redD[s][e]; rs += redR[s][e]; }
    float rl = 1.f;
    if (iter > 0) {
      float rlp = lbuf[idx];
      float ap  = rlp * RCPF(dtot[idx] + EPSC);
      rl = fmaxf(rlp - ap * rs, 0.f);
    }
    lbuf[idx] = rl;
    dtot[idx] = dnew;
    abuf[idx] = rl * RCPF(dnew + EPSC);
  }
}

// ---------------------------------------------------------------------------
// R2 (wide): same slicing.  u = rr*min(rr/(rr*s0+eps),1); urbuf = (u, rr');
// cost partial (32 elements) -> one atomicAdd(out + b) per block.
// ---------------------------------------------------------------------------
template<int NSEG, bool LAST>
__global__ __launch_bounds__(256) void r2_kernel(
    const float* __restrict__ s0P, const float* __restrict__ s1P,
    float2* __restrict__ urbuf, float* __restrict__ out, int iter)
{
  constexpr int SL = 8, EPB = 32, PPS = NSEG / SL;
  __shared__ float redA[SL][EPB];
  __shared__ float redB[SL][EPB];

  const int e  = threadIdx.x & (EPB - 1);
  const int sl = threadIdx.x / EPB;
  const int idx = blockIdx.x * EPB + e;
  const int b = idx >> 12;
  const size_t plane = (size_t)NB * NPTS;

  float a0 = 0.f, a1 = 0.f;
#pragma unroll
  for (int s = 0; s < PPS; ++s) {
    a0 += s0P[(size_t)(sl * PPS + s) * plane + idx];
    a1 += s1P[(size_t)(sl * PPS + s) * plane + idx];
  }
  redA[sl][e] = a0;
  redB[sl][e] = a1;
  __syncthreads();

  float cpart = 0.f;
  if (sl == 0) {
    float s0 = 0.f, s1 = 0.f;
#pragma unroll
    for (int s = 0; s < SL; ++s) { s0 += redA[s][e]; s1 += redB[s][e]; }
    float rr    = (iter == 0) ? 1.f : urbuf[idx].y;
    float sumr  = fmaf(rr, s0, EPSC);
    float ratio = fminf(rr * RCPF(sumr), 1.f);
    float u     = rr * ratio;
    if (!LAST) urbuf[idx] = make_float2(u, fmaxf(rr - u * s0, 0.f));
    cpart = u * s1;
  }
  __syncthreads();
  if (sl == 0) redA[0][e] = cpart;
  __syncthreads();
  if (threadIdx.x == 0) {
    float acc = 0.f;
#pragma unroll
    for (int j = 0; j < EPB; ++j) acc += redA[0][j];
    atomicAdd(out + b, acc);
  }
}

// ---------------------------------------------------------------------------
template<int NSEG>
static void run_all(const float* x1, const float* x2, float* out, float* ws,
                    hipStream_t stream)
{
  constexpr int CHUNK = NPTS / NSEG;
  const size_t plane = (size_t)NB * NPTS;

  float*  bufA = ws;                                      // NSEG planes
  float*  bufB = bufA + (size_t)NSEG * plane;             // NSEG planes
  float4* x1p  = (float4*)(bufB + (size_t)NSEG * plane);  // 4 planes
  float4* x2p  = x1p + plane;                             // 4 planes
  float*  dtot = (float*)(x2p + plane);
  float*  lbuf = dtot + plane;
  float*  abuf = lbuf + plane;
  float2* urbuf = (float2*)(abuf + plane);                // 2 planes
  float4* bb   = (float4*)(urbuf + plane);                // 2048 float4
  float4* bb1  = bb;
  float4* bb2  = bb + (size_t)NB * 128;

  const double L2E = 1.4426950408889634074;
  const double lv[10] = {-16384.0, -4096.0, -1024.0, -256.0, -64.0,
                         -16.0, -4.0, -1.0, -0.25, 0.0};
  float scl[10], inv_s[10];
  for (int i = 0; i < 10; ++i) {
    double c2 = lv[i] * L2E;
    scl[i]   = (i == 9) ? 1.f : (float)sqrt(-c2);
    inv_s[i] = (i == 9) ? 1.f : (float)(1.0 / sqrt(-c2));
  }

  dim3 gmain(NPTS / (TPB * MBLK), NSEG, NB), bmain(TPB);
  dim3 gr(NB * NPTS / 32), br(256);

  sort_kernel<<<dim3(2, NB), bmain, 0, stream>>>(x1, x2, x1p, x2p, bb);

  // A_0: denom_0 partials (level -16384), zero out[]
  ca_kernel<0, true, true, CHUNK><<<gmain, bmain, 0, stream>>>(
      x2p, x1p, urbuf, bufA, bufB, bb2, out, scl[0]);

  for (int i = 0; i < 10; ++i) {
    r1_kernel<NSEG><<<gr, br, 0, stream>>>(bufA, bufB, lbuf, dtot, abuf, i);

    if (i <= 5)
      b_kernel<0, true, true, CHUNK><<<gmain, bmain, 0, stream>>>(
          x1p, abuf, x2p, bufA, bufB, bb1, scl[i], inv_s[i]);
    else if (i <= 8)
      b_kernel<0, false, false, CHUNK><<<gmain, bmain, 0, stream>>>(
          x1p, abuf, x2p, bufA, bufB, bb1, scl[i], inv_s[i]);
    else
      b_kernel<1, false, false, CHUNK><<<gmain, bmain, 0, stream>>>(
          x1p, abuf, x2p, bufA, bufB, bb1, 1.f, 1.f);

    if (i < 9)
      r2_kernel<NSEG, false><<<gr, br, 0, stream>>>(bufA, bufB, urbuf, out, i);
    else
      r2_kernel<NSEG, true><<<gr, br, 0, stream>>>(bufA, bufB, urbuf, out, i);

    if (i <= 4)
      ca_kernel<1, true, true, CHUNK><<<gmain, bmain, 0, stream>>>(
          x2p, x1p, urbuf, bufA, bufB, bb2, out, scl[i + 1]);
    else if (i == 5)
      ca_kernel<1, true, false, CHUNK><<<gmain, bmain, 0, stream>>>(
          x2p, x1p, urbuf, bufA, bufB, bb2, out, scl[i + 1]);
    else if (i <= 7)
      ca_kernel<1, false, false, CHUNK><<<gmain, bmain, 0, stream>>>(
          x2p, x1p, urbuf, bufA, bufB, bb2, out, scl[i + 1]);
    else if (i == 8)
      ca_kernel<2, false, false, CHUNK><<<gmain, bmain, 0, stream>>>(
          x2p, x1p, urbuf, bufA, bufB, bb2, out, scl[8]);
  }
}

extern "C" void kernel_launch(void* const* d_in, const int* in_sizes, int n_in,
                              void* d_out, int out_size, void* d_ws, size_t ws_size,
                              hipStream_t stream) {
  const float* x1 = (const float*)d_in[0];
  const float* x2 = (const float*)d_in[1];
  float* out = (float*)d_out;
  float* ws  = (float*)d_ws;

  const size_t plane = (size_t)NB * NPTS;
  auto need = [&](int nseg) {
    return (size_t)(2 * nseg + 13) * plane * sizeof(float)
         + (size_t)2048 * sizeof(float4);
  };

  if (ws_size >= need(64))      run_all<64>(x1, x2, out, ws, stream);
  else if (ws_size >= need(32)) run_all<32>(x1, x2, out, ws, stream);
  else                          run_all<16>(x1, x2, out, ws, stream);
}

// Round 13
// 983.610 us; speedup vs baseline: 1.6780x; 1.0042x over previous
//
#include <hip/hip_runtime.h>

#define NPTS 4096
#define NB   8
#define TPB  256
#define MBLK 4
#define EPSC 1e-9f

#define EXP2(x)  __builtin_amdgcn_exp2f(x)
#define RCPF(x)  __builtin_amdgcn_rcpf(x)
#define SQRTF(x) __builtin_amdgcn_sqrtf(x)

// ---------------------------------------------------------------------------
// Morton bucket sort (4 bits/axis) per (set, batch) + per-8-point sub-bboxes
// (512 per set,b). Any permutation is exactly correct (cost is a set-pairwise
// sum); sorting only improves skip coherence.
// ---------------------------------------------------------------------------
__global__ __launch_bounds__(TPB) void sort_kernel(
    const float* __restrict__ x1, const float* __restrict__ x2,
    float4* __restrict__ x1p, float4* __restrict__ x2p,
    float4* __restrict__ bb8)           // [2][NB][512][2] (min,max)
{
  __shared__ unsigned int   hist[4096];
  __shared__ unsigned short codes[4096];
  __shared__ unsigned int   part[TPB];

  const int set = blockIdx.x, b = blockIdx.y;
  const float* src = set ? x2 : x1;
  float4* dst = set ? x2p : x1p;
  const int tid = threadIdx.x;

  for (int i = tid; i < 4096; i += TPB) hist[i] = 0;
  __syncthreads();

  for (int j = 0; j < NPTS / TPB; ++j) {
    int n = j * TPB + tid;
    const float* p = src + ((size_t)b * NPTS + n) * 3;
    int qx = min(max((int)((p[0] + 4.f) * 2.f), 0), 15);
    int qy = min(max((int)((p[1] + 4.f) * 2.f), 0), 15);
    int qz = min(max((int)((p[2] + 4.f) * 2.f), 0), 15);
    auto ex = [](int v) {
      return (v & 1) | ((v & 2) << 2) | ((v & 4) << 4) | ((v & 8) << 6);
    };
    int code = ex(qx) | (ex(qy) << 1) | (ex(qz) << 2);
    codes[n] = (unsigned short)code;
    atomicAdd(&hist[code], 1u);
  }
  __syncthreads();

  unsigned int loc[16], s = 0;
#pragma unroll
  for (int j = 0; j < 16; ++j) { loc[j] = s; s += hist[tid * 16 + j]; }
  part[tid] = s;
  __syncthreads();
  if (tid == 0) {
    unsigned int run = 0;
    for (int t = 0; t < TPB; ++t) { unsigned int v = part[t]; part[t] = run; run += v; }
  }
  __syncthreads();
  {
    unsigned int base = part[tid];
#pragma unroll
    for (int j = 0; j < 16; ++j) hist[tid * 16 + j] = base + loc[j];
  }
  __syncthreads();

  for (int j = 0; j < NPTS / TPB; ++j) {
    int n = j * TPB + tid;
    const float* p = src + ((size_t)b * NPTS + n) * 3;
    unsigned int pos = atomicAdd(&hist[codes[n]], 1u);
    dst[(size_t)b * NPTS + pos] = make_float4(p[0], p[1], p[2], 0.f);
  }
  __syncthreads();   // vmem drained at barrier; sorted data visible

  for (int g = tid; g < 512; g += TPB) {   // 8-pt sub-bboxes
    float mnx = 1e30f, mny = 1e30f, mnz = 1e30f;
    float mxx = -1e30f, mxy = -1e30f, mxz = -1e30f;
#pragma unroll
    for (int j = 0; j < 8; ++j) {
      float4 p = dst[(size_t)b * NPTS + g * 8 + j];
      mnx = fminf(mnx, p.x); mxx = fmaxf(mxx, p.x);
      mny = fminf(mny, p.y); mxy = fmaxf(mxy, p.y);
      mnz = fminf(mnz, p.z); mxz = fmaxf(mxz, p.z);
    }
    size_t bi = ((size_t)(set * NB + b) * 512 + g) * 2;
    bb8[bi + 0] = make_float4(mnx, mny, mnz, 0.f);
    bb8[bi + 1] = make_float4(mxx, mxy, mxz, 0.f);
  }
}

// ---------------------------------------------------------------------------
// CA kernel: C_i (rsum[n] = sum_m e_i*u[m], e_i = e_{i+1}^4) fused with
// A_{i+1} (denom[n] = sum_m e_{i+1}*rr[m]).  Dot-product form, partial-plane
// stores.  MODE 0: A_0 only (zeroes out).  MODE 2: i=8 (A-part = sum rr,
// precomputed as a wave reduce; C-part e_8).
// SUBCULL: wave-uniform 8-pt sub-granule skip via ballot mask.
// ---------------------------------------------------------------------------
template<int MODE, bool SUBCULL, int CHUNK>
__global__ __launch_bounds__(TPB) void ca_kernel(
    const float4* __restrict__ x2p, const float4* __restrict__ x1p,
    const float2* __restrict__ urbuf,
    float* __restrict__ dbufP, float* __restrict__ rsumP,
    const float4* __restrict__ bb8s,    // staged-set sub-bboxes
    float* __restrict__ out, float sc)
{
  __shared__ float4 x2s[CHUNK];
  __shared__ float2 urs[CHUNK];

  const int tid = threadIdx.x;
  const int nchunk = blockIdx.x, mseg = blockIdx.y, b = blockIdx.z;

  if (MODE == 0 && nchunk == 0 && mseg == 0 && tid == 0) out[b] = 0.f;

  for (int mm = tid; mm < CHUNK; mm += TPB) {
    int m = mseg * CHUNK + mm;
    float4 q = x2p[(size_t)b * NPTS + m];
    float sx = sc * q.x, sy = sc * q.y, sz = sc * q.z;
    float nq = fmaf(sz, sz, fmaf(sy, sy, sx * sx));
    x2s[mm] = make_float4(-2.f * sx, -2.f * sy, -2.f * sz, nq);
    urs[mm] = (MODE == 0) ? make_float2(0.f, 1.f) : urbuf[(size_t)b * NPTS + m];
  }
  __syncthreads();

  const int n0 = nchunk * (TPB * MBLK) + tid * MBLK;
  float px[MBLK], py[MBLK], pz[MBLK], np[MBLK], dacc[MBLK], racc[MBLK];
#pragma unroll
  for (int k = 0; k < MBLK; ++k) {
    float4 p = x1p[(size_t)b * NPTS + n0 + k];
    px[k] = sc * p.x; py[k] = sc * p.y; pz[k] = sc * p.z;
    np[k] = fmaf(pz[k], pz[k], fmaf(py[k], py[k], px[k] * px[k]));
    dacc[k] = 0.f; racc[k] = 0.f;
  }

  float rrsum = 0.f;
  if (MODE == 2) {           // A-part at level 0: denom += sum_m rr (constant)
    float v = 0.f;
    for (int l = (tid & 63); l < CHUNK; l += 64) v += urs[l].y;
#pragma unroll
    for (int off = 1; off < 64; off <<= 1) v += __shfl_xor(v, off);
    rrsum = v;
  }

  auto proc = [&](int mm) {
    float4 q = x2s[mm];
    float2 ur = urs[mm];
    float ds2[MBLK];
#pragma unroll
    for (int k = 0; k < MBLK; ++k)
      ds2[k] = fmaf(q.x, px[k], fmaf(q.y, py[k], fmaf(q.z, pz[k], np[k] + q.w)));
    if (MODE == 2) {
#pragma unroll
      for (int k = 0; k < MBLK; ++k)
        racc[k] = fmaf(EXP2(-ds2[k]), ur.x, racc[k]);
    } else {
#pragma unroll
      for (int k = 0; k < MBLK; ++k) {
        float en = EXP2(-ds2[k]);
        dacc[k] = fmaf(en, ur.y, dacc[k]);
        if (MODE == 1) { float e2 = en * en; racc[k] = fmaf(e2 * e2, ur.x, racc[k]); }
      }
    }
  };

  if (SUBCULL) {
    // wave bbox of owned (scaled) points
    float mnx = fminf(fminf(px[0], px[1]), fminf(px[2], px[3]));
    float mny = fminf(fminf(py[0], py[1]), fminf(py[2], py[3]));
    float mnz = fminf(fminf(pz[0], pz[1]), fminf(pz[2], pz[3]));
    float mxx = fmaxf(fmaxf(px[0], px[1]), fmaxf(px[2], px[3]));
    float mxy = fmaxf(fmaxf(py[0], py[1]), fmaxf(py[2], py[3]));
    float mxz = fmaxf(fmaxf(pz[0], pz[1]), fmaxf(pz[2], pz[3]));
#pragma unroll
    for (int off = 1; off < 64; off <<= 1) {
      mnx = fminf(mnx, __shfl_xor(mnx, off));
      mny = fminf(mny, __shfl_xor(mny, off));
      mnz = fminf(mnz, __shfl_xor(mnz, off));
      mxx = fmaxf(mxx, __shfl_xor(mxx, off));
      mxy = fmaxf(mxy, __shfl_xor(mxy, off));
      mxz = fmaxf(mxz, __shfl_xor(mxz, off));
    }
    constexpr int NSUB = CHUNK / 8;
    const int lane = tid & 63;
    bool go = false;
    if (lane < NSUB) {
      size_t bi = ((size_t)b * 512 + mseg * NSUB + lane) * 2;
      float4 smin = bb8s[bi], smax = bb8s[bi + 1];
      float gx = fmaxf(0.f, fmaxf(sc * smin.x - mxx, mnx - sc * smax.x));
      float gy = fmaxf(0.f, fmaxf(sc * smin.y - mxy, mny - sc * smax.y));
      float gz = fmaxf(0.f, fmaxf(sc * smin.z - mxz, mnz - sc * smax.z));
      go = fmaf(gx, gx, fmaf(gy, gy, gz * gz)) < 126.f;
    }
    unsigned long long mask = __ballot(go);
    for (int s = 0; s < NSUB; ++s) {
      if (!((mask >> s) & 1)) continue;   // wave-uniform skip of 8 staged pts
#pragma unroll
      for (int j = 0; j < 8; ++j) proc(s * 8 + j);
    }
  } else {
#pragma unroll 4
    for (int mm = 0; mm < CHUNK; ++mm) proc(mm);
  }

  size_t base = ((size_t)mseg * NB + b) * NPTS + n0;
  if (MODE == 2) {
#pragma unroll
    for (int k = 0; k < MBLK; ++k) dacc[k] = rrsum;
  }
  *(float4*)&dbufP[base] = make_float4(dacc[0], dacc[1], dacc[2], dacc[3]);
  if (MODE >= 1)
    *(float4*)&rsumP[base] = make_float4(racc[0], racc[1], racc[2], racc[3]);
}

// ---------------------------------------------------------------------------
// B kernel: s0[m] = sum_n a*e_i, s1[m] = sum_n a*e_i*dist (de-scaled once).
// LVL0: i=9 (e=1, sc=1): s0 = sum a (wave-reduce constant), s1 loop only.
// ---------------------------------------------------------------------------
template<int LVL0, bool SUBCULL, int CHUNK>
__global__ __launch_bounds__(TPB) void b_kernel(
    const float4* __restrict__ x1p, const float* __restrict__ abuf,
    const float4* __restrict__ x2p,
    float* __restrict__ s0P, float* __restrict__ s1P,
    const float4* __restrict__ bb8s, float sc, float inv_s)
{
  __shared__ float4 x1s[CHUNK];
  __shared__ float  as_[CHUNK];

  const int tid = threadIdx.x;
  const int mchunk = blockIdx.x, nsegi = blockIdx.y, b = blockIdx.z;

  for (int nn = tid; nn < CHUNK; nn += TPB) {
    int n = nsegi * CHUNK + nn;
    float4 p = x1p[(size_t)b * NPTS + n];
    float sx = sc * p.x, sy = sc * p.y, sz = sc * p.z;
    float npv = fmaf(sz, sz, fmaf(sy, sy, sx * sx));
    x1s[nn] = make_float4(-2.f * sx, -2.f * sy, -2.f * sz, npv);
    as_[nn] = abuf[(size_t)b * NPTS + n];
  }
  __syncthreads();

  const int m0 = mchunk * (TPB * MBLK) + tid * MBLK;
  float qx[MBLK], qy[MBLK], qz[MBLK], nq[MBLK], s0a[MBLK], s1a[MBLK];
#pragma unroll
  for (int k = 0; k < MBLK; ++k) {
    float4 q = x2p[(size_t)b * NPTS + m0 + k];
    qx[k] = sc * q.x; qy[k] = sc * q.y; qz[k] = sc * q.z;
    nq[k] = fmaf(qz[k], qz[k], fmaf(qy[k], qy[k], qx[k] * qx[k]));
    s0a[k] = 0.f; s1a[k] = 0.f;
  }

  float asum = 0.f;
  if (LVL0) {                // s0 = sum_n a (constant across owned m)
    float v = 0.f;
    for (int l = (tid & 63); l < CHUNK; l += 64) v += as_[l];
#pragma unroll
    for (int off = 1; off < 64; off <<= 1) v += __shfl_xor(v, off);
    asum = v;
  }

  auto proc = [&](int nn) {
    float4 p = x1s[nn];
    float av = as_[nn];
    float ds2[MBLK];
#pragma unroll
    for (int k = 0; k < MBLK; ++k)
      ds2[k] = fmaf(p.x, qx[k], fmaf(p.y, qy[k], fmaf(p.z, qz[k], nq[k] + p.w)));
    if (LVL0) {
#pragma unroll
      for (int k = 0; k < MBLK; ++k)
        s1a[k] = fmaf(av, SQRTF(__builtin_fabsf(ds2[k])), s1a[k]);
    } else {
#pragma unroll
      for (int k = 0; k < MBLK; ++k) {
        float tt = av * EXP2(-ds2[k]);
        s0a[k] += tt;
        s1a[k] = fmaf(tt, SQRTF(__builtin_fabsf(ds2[k])), s1a[k]);
      }
    }
  };

  if (SUBCULL) {
    float mnx = fminf(fminf(qx[0], qx[1]), fminf(qx[2], qx[3]));
    float mny = fminf(fminf(qy[0], qy[1]), fminf(qy[2], qy[3]));
    float mnz = fminf(fminf(qz[0], qz[1]), fminf(qz[2], qz[3]));
    float mxx = fmaxf(fmaxf(qx[0], qx[1]), fmaxf(qx[2], qx[3]));
    float mxy = fmaxf(fmaxf(qy[0], qy[1]), fmaxf(qy[2], qy[3]));
    float mxz = fmaxf(fmaxf(qz[0], qz[1]), fmaxf(qz[2], qz[3]));
#pragma unroll
    for (int off = 1; off < 64; off <<= 1) {
      mnx = fminf(mnx, __shfl_xor(mnx, off));
      mny = fminf(mny, __shfl_xor(mny, off));
      mnz = fminf(mnz, __shfl_xor(mnz, off));
      mxx = fmaxf(mxx, __shfl_xor(mxx, off));
      mxy = fmaxf(mxy, __shfl_xor(mxy, off));
      mxz = fmaxf(mxz, __shfl_xor(mxz, off));
    }
    constexpr int NSUB = CHUNK / 8;
    const int lane = tid & 63;
    bool go = false;
    if (lane < NSUB) {
      size_t bi = ((size_t)b * 512 + nsegi * NSUB + lane) * 2;
      float4 smin = bb8s[bi], smax = bb8s[bi + 1];
      float gx = fmaxf(0.f, fmaxf(sc * smin.x - mxx, mnx - sc * smax.x));
      float gy = fmaxf(0.f, fmaxf(sc * smin.y - mxy, mny - sc * smax.y));
      float gz = fmaxf(0.f, fmaxf(sc * smin.z - mxz, mnz - sc * smax.z));
      go = fmaf(gx, gx, fmaf(gy, gy, gz * gz)) < 126.f;
    }
    unsigned long long mask = __ballot(go);
    for (int s = 0; s < NSUB; ++s) {
      if (!((mask >> s) & 1)) continue;
#pragma unroll
      for (int j = 0; j < 8; ++j) proc(s * 8 + j);
    }
  } else {
#pragma unroll 4
    for (int nn = 0; nn < CHUNK; ++nn) proc(nn);
  }

  size_t base = ((size_t)nsegi * NB + b) * NPTS + m0;
  if (LVL0) {
#pragma unroll
    for (int k = 0; k < MBLK; ++k) s0a[k] = asum;
  }
  *(float4*)&s0P[base] = make_float4(s0a[0], s0a[1], s0a[2], s0a[3]);
  *(float4*)&s1P[base] = make_float4(s1a[0] * inv_s, s1a[1] * inv_s,
                                     s1a[2] * inv_s, s1a[3] * inv_s);
}

// ---------------------------------------------------------------------------
// R1 (wide): block = 32 elements x 8 seg-slices (256 thr); coalesced plane
// sums; slice 0 does the remainL recurrence and a_i = rl/(denom+eps).
// ---------------------------------------------------------------------------
template<int NSEG>
__global__ __launch_bounds__(256) void r1_kernel(
    const float* __restrict__ dbufP, const float* __restrict__ rsumP,
    float* __restrict__ lbuf, float* __restrict__ dtot,
    float* __restrict__ abuf, int iter)
{
  constexpr int SL = 8, EPB = 32, PPS = NSEG / SL;
  __shared__ float redD[SL][EPB];
  __shared__ float redR[SL][EPB];

  const int e  = threadIdx.x & (EPB - 1);
  const int sl = threadIdx.x / EPB;
  const int idx = blockIdx.x * EPB + e;
  const size_t plane = (size_t)NB * NPTS;

  float ad = 0.f, ar = 0.f;
#pragma unroll
  for (int s = 0; s < PPS; ++s)
    ad += dbufP[(size_t)(sl * PPS + s) * plane + idx];
  if (iter > 0) {
#pragma unroll
    for (int s = 0; s < PPS; ++s)
      ar += rsumP[(size_t)(sl * PPS + s) * plane + idx];
  }
  redD[sl][e] = ad;
  redR[sl][e] = ar;
  __syncthreads();

  if (sl == 0) {
    float dnew = 0.f, rs = 0.f;
#pragma unroll
    for (int s = 0; s < SL; ++s) { dnew += redD[s][e]; rs += redR[s][e]; }
    float rl = 1.f;
    if (iter > 0) {
      float rlp = lbuf[idx];
      float ap  = rlp * RCPF(dtot[idx] + EPSC);
      rl = fmaxf(rlp - ap * rs, 0.f);
    }
    lbuf[idx] = rl;
    dtot[idx] = dnew;
    abuf[idx] = rl * RCPF(dnew + EPSC);
  }
}

// ---------------------------------------------------------------------------
// R2 (wide): u = rr*min(rr/(rr*s0+eps),1); urbuf = (u, rr'); cost partial ->
// one atomicAdd(out + b) per block.
// ---------------------------------------------------------------------------
template<int NSEG, bool LAST>
__global__ __launch_bounds__(256) void r2_kernel(
    const float* __restrict__ s0P, const float* __restrict__ s1P,
    float2* __restrict__ urbuf, float* __restrict__ out, int iter)
{
  constexpr int SL = 8, EPB = 32, PPS = NSEG / SL;
  __shared__ float redA[SL][EPB];
  __shared__ float redB[SL][EPB];

  const int e  = threadIdx.x & (EPB - 1);
  const int sl = threadIdx.x / EPB;
  const int idx = blockIdx.x * EPB + e;
  const int b = idx >> 12;
  const size_t plane = (size_t)NB * NPTS;

  float a0 = 0.f, a1 = 0.f;
#pragma unroll
  for (int s = 0; s < PPS; ++s) {
    a0 += s0P[(size_t)(sl * PPS + s) * plane + idx];
    a1 += s1P[(size_t)(sl * PPS + s) * plane + idx];
  }
  redA[sl][e] = a0;
  redB[sl][e] = a1;
  __syncthreads();

  float cpart = 0.f;
  if (sl == 0) {
    float s0 = 0.f, s1 = 0.f;
#pragma unroll
    for (int s = 0; s < SL; ++s) { s0 += redA[s][e]; s1 += redB[s][e]; }
    float rr    = (iter == 0) ? 1.f : urbuf[idx].y;
    float sumr  = fmaf(rr, s0, EPSC);
    float ratio = fminf(rr * RCPF(sumr), 1.f);
    float u     = rr * ratio;
    if (!LAST) urbuf[idx] = make_float2(u, fmaxf(rr - u * s0, 0.f));
    cpart = u * s1;
  }
  __syncthreads();
  if (sl == 0) redA[0][e] = cpart;
  __syncthreads();
  if (threadIdx.x == 0) {
    float acc = 0.f;
#pragma unroll
    for (int j = 0; j < EPB; ++j) acc += redA[0][j];
    atomicAdd(out + b, acc);
  }
}

// ---------------------------------------------------------------------------
template<int NSEG>
static void run_all(const float* x1, const float* x2, float* out, float* ws,
                    hipStream_t stream)
{
  constexpr int CHUNK = NPTS / NSEG;
  const size_t plane = (size_t)NB * NPTS;

  float*  bufA = ws;                                      // NSEG planes
  float*  bufB = bufA + (size_t)NSEG * plane;             // NSEG planes
  float4* x1p  = (float4*)(bufB + (size_t)NSEG * plane);  // 4 planes
  float4* x2p  = x1p + plane;                             // 4 planes
  float*  dtot = (float*)(x2p + plane);
  float*  lbuf = dtot + plane;
  float*  abuf = lbuf + plane;
  float2* urbuf = (float2*)(abuf + plane);                // 2 planes
  float4* bb8  = (float4*)(urbuf + plane);                // 2*NB*512*2 float4
  float4* bb8_1 = bb8;                                    // set 0 (x1)
  float4* bb8_2 = bb8 + (size_t)NB * 512 * 2;             // set 1 (x2)

  const double L2E = 1.4426950408889634074;
  const double lv[10] = {-16384.0, -4096.0, -1024.0, -256.0, -64.0,
                         -16.0, -4.0, -1.0, -0.25, 0.0};
  float scl[10], inv_s[10];
  for (int i = 0; i < 10; ++i) {
    double c2 = lv[i] * L2E;
    scl[i]   = (i == 9) ? 1.f : (float)sqrt(-c2);
    inv_s[i] = (i == 9) ? 1.f : (float)(1.0 / sqrt(-c2));
  }

  dim3 gmain(NPTS / (TPB * MBLK), NSEG, NB), bmain(TPB);
  dim3 gr(NB * NPTS / 32), br(256);

  sort_kernel<<<dim3(2, NB), bmain, 0, stream>>>(x1, x2, x1p, x2p, bb8);

  // A_0: denom_0 partials (level -16384), zero out[]
  ca_kernel<0, true, CHUNK><<<gmain, bmain, 0, stream>>>(
      x2p, x1p, urbuf, bufA, bufB, bb8_2, out, scl[0]);

  for (int i = 0; i < 10; ++i) {
    r1_kernel<NSEG><<<gr, br, 0, stream>>>(bufA, bufB, lbuf, dtot, abuf, i);

    if (i <= 6)
      b_kernel<0, true, CHUNK><<<gmain, bmain, 0, stream>>>(
          x1p, abuf, x2p, bufA, bufB, bb8_1, scl[i], inv_s[i]);
    else if (i <= 8)
      b_kernel<0, false, CHUNK><<<gmain, bmain, 0, stream>>>(
          x1p, abuf, x2p, bufA, bufB, bb8_1, scl[i], inv_s[i]);
    else
      b_kernel<1, false, CHUNK><<<gmain, bmain, 0, stream>>>(
          x1p, abuf, x2p, bufA, bufB, bb8_1, 1.f, 1.f);

    if (i < 9)
      r2_kernel<NSEG, false><<<gr, br, 0, stream>>>(bufA, bufB, urbuf, out, i);
    else
      r2_kernel<NSEG, true><<<gr, br, 0, stream>>>(bufA, bufB, urbuf, out, i);

    if (i <= 5)
      ca_kernel<1, true, CHUNK><<<gmain, bmain, 0, stream>>>(
          x2p, x1p, urbuf, bufA, bufB, bb8_2, out, scl[i + 1]);
    else if (i <= 7)
      ca_kernel<1, false, CHUNK><<<gmain, bmain, 0, stream>>>(
          x2p, x1p, urbuf, bufA, bufB, bb8_2, out, scl[i + 1]);
    else if (i == 8)
      ca_kernel<2, false, CHUNK><<<gmain, bmain, 0, stream>>>(
          x2p, x1p, urbuf, bufA, bufB, bb8_2, out, scl[8]);
  }
}

extern "C" void kernel_launch(void* const* d_in, const int* in_sizes, int n_in,
                              void* d_out, int out_size, void* d_ws, size_t ws_size,
                              hipStream_t stream) {
  const float* x1 = (const float*)d_in[0];
  const float* x2 = (const float*)d_in[1];
  float* out = (float*)d_out;
  float* ws  = (float*)d_ws;

  const size_t plane = (size_t)NB * NPTS;
  auto need = [&](int nseg) {
    return (size_t)(2 * nseg + 13) * plane * sizeof(float)
         + (size_t)2 * NB * 512 * 2 * sizeof(float4);
  };

  if (ws_size >= need(64))      run_all<64>(x1, x2, out, ws, stream);
  else if (ws_size >= need(32)) run_all<32>(x1, x2, out, ws, stream);
  else                          run_all<16>(x1, x2, out, ws, stream);
}

// Round 14
// 979.639 us; speedup vs baseline: 1.6848x; 1.0041x over previous
//
#include <hip/hip_runtime.h>

#define NPTS 4096
#define NB   8
#define TPB  256
#define MBLK 8
#define EPSC 1e-9f

#define EXP2(x)  __builtin_amdgcn_exp2f(x)
#define RCPF(x)  __builtin_amdgcn_rcpf(x)
#define SQRTF(x) __builtin_amdgcn_sqrtf(x)

// ---------------------------------------------------------------------------
// Morton bucket sort (4 bits/axis, 4096 buckets) per (set, batch), packs to
// float4. Any permutation is exactly correct (cost is a set-pairwise sum);
// sorting keeps the whole-wave underflow skip coherent for early levels.
// ---------------------------------------------------------------------------
__global__ __launch_bounds__(TPB) void sort_kernel(
    const float* __restrict__ x1, const float* __restrict__ x2,
    float4* __restrict__ x1p, float4* __restrict__ x2p)
{
  __shared__ unsigned int   hist[4096];
  __shared__ unsigned short codes[4096];
  __shared__ unsigned int   part[TPB];

  const int set = blockIdx.x, b = blockIdx.y;
  const float* src = set ? x2 : x1;
  float4* dst = set ? x2p : x1p;
  const int tid = threadIdx.x;

  for (int i = tid; i < 4096; i += TPB) hist[i] = 0;
  __syncthreads();

  for (int j = 0; j < NPTS / TPB; ++j) {
    int n = j * TPB + tid;
    const float* p = src + ((size_t)b * NPTS + n) * 3;
    int qx = min(max((int)((p[0] + 4.f) * 2.f), 0), 15);
    int qy = min(max((int)((p[1] + 4.f) * 2.f), 0), 15);
    int qz = min(max((int)((p[2] + 4.f) * 2.f), 0), 15);
    auto ex = [](int v) {
      return (v & 1) | ((v & 2) << 2) | ((v & 4) << 4) | ((v & 8) << 6);
    };
    int code = ex(qx) | (ex(qy) << 1) | (ex(qz) << 2);
    codes[n] = (unsigned short)code;
    atomicAdd(&hist[code], 1u);
  }
  __syncthreads();

  unsigned int loc[16], s = 0;
#pragma unroll
  for (int j = 0; j < 16; ++j) { loc[j] = s; s += hist[tid * 16 + j]; }
  part[tid] = s;
  __syncthreads();
  if (tid == 0) {
    unsigned int run = 0;
    for (int t = 0; t < TPB; ++t) { unsigned int v = part[t]; part[t] = run; run += v; }
  }
  __syncthreads();
  {
    unsigned int base = part[tid];
#pragma unroll
    for (int j = 0; j < 16; ++j) hist[tid * 16 + j] = base + loc[j];
  }
  __syncthreads();

  for (int j = 0; j < NPTS / TPB; ++j) {
    int n = j * TPB + tid;
    const float* p = src + ((size_t)b * NPTS + n) * 3;
    unsigned int pos = atomicAdd(&hist[codes[n]], 1u);
    dst[(size_t)b * NPTS + pos] = make_float4(p[0], p[1], p[2], 0.f);
  }
}

// ---------------------------------------------------------------------------
// CA kernel: C_i (rsum[n] = sum_m e_i*u[m], e_i = e_{i+1}^4) fused with
// A_{i+1} (denom[n] = sum_m e_{i+1}*rr[m]).  Dot-product form, partial-plane
// float4 stores.  MODE 0: A_0 only (zeroes out).  MODE 2: i=8 (A-part =
// sum rr via wave reduce; C-part e_8 loop).
// PSKIP (levels <= -1024 only): whole-wave dmin branch -- skips the exp/acc
// block (exact: all skipped exps are f32-underflow zeros).
// Thread owns MBLK=8 contiguous sorted points; CHUNK staged in LDS.
// ---------------------------------------------------------------------------
template<int MODE, bool PSKIP, int CHUNK>
__global__ __launch_bounds__(TPB) void ca_kernel(
    const float4* __restrict__ x2p, const float4* __restrict__ x1p,
    const float2* __restrict__ urbuf,
    float* __restrict__ dbufP, float* __restrict__ rsumP,
    float* __restrict__ out, float sc)
{
  __shared__ float4 x2s[CHUNK];
  __shared__ float2 urs[CHUNK];

  const int tid = threadIdx.x;
  const int nchunk = blockIdx.x, mseg = blockIdx.y, b = blockIdx.z;

  if (MODE == 0 && nchunk == 0 && mseg == 0 && tid == 0) out[b] = 0.f;

  for (int mm = tid; mm < CHUNK; mm += TPB) {
    int m = mseg * CHUNK + mm;
    float4 q = x2p[(size_t)b * NPTS + m];
    float sx = sc * q.x, sy = sc * q.y, sz = sc * q.z;
    float nq = fmaf(sz, sz, fmaf(sy, sy, sx * sx));
    x2s[mm] = make_float4(-2.f * sx, -2.f * sy, -2.f * sz, nq);
    urs[mm] = (MODE == 0) ? make_float2(0.f, 1.f) : urbuf[(size_t)b * NPTS + m];
  }
  __syncthreads();

  const int n0 = nchunk * (TPB * MBLK) + tid * MBLK;
  float px[MBLK], py[MBLK], pz[MBLK], np[MBLK], dacc[MBLK], racc[MBLK];
#pragma unroll
  for (int k = 0; k < MBLK; ++k) {
    float4 p = x1p[(size_t)b * NPTS + n0 + k];
    px[k] = sc * p.x; py[k] = sc * p.y; pz[k] = sc * p.z;
    np[k] = fmaf(pz[k], pz[k], fmaf(py[k], py[k], px[k] * px[k]));
    dacc[k] = 0.f; racc[k] = 0.f;
  }

  float rrsum = 0.f;
  if (MODE == 2) {           // A-part at level 0: denom = sum_m rr (constant)
    float v = 0.f;
    for (int l = (tid & 63); l < CHUNK; l += 64) v += urs[l].y;
#pragma unroll
    for (int off = 1; off < 64; off <<= 1) v += __shfl_xor(v, off);
    rrsum = v;
  }

#pragma unroll 2
  for (int mm = 0; mm < CHUNK; ++mm) {
    float4 q = x2s[mm];
    float2 ur = urs[mm];
    float ds2[MBLK];
#pragma unroll
    for (int k = 0; k < MBLK; ++k)
      ds2[k] = fmaf(q.x, px[k], fmaf(q.y, py[k], fmaf(q.z, pz[k], np[k] + q.w)));
    if (MODE == 2) {
#pragma unroll
      for (int k = 0; k < MBLK; ++k)
        racc[k] = fmaf(EXP2(-ds2[k]), ur.x, racc[k]);
    } else {
      bool go = true;
      if (PSKIP) {
        float dmin = fminf(fminf(fminf(ds2[0], ds2[1]), fminf(ds2[2], ds2[3])),
                           fminf(fminf(ds2[4], ds2[5]), fminf(ds2[6], ds2[7])));
        go = dmin < 126.f;
      }
      if (go) {
#pragma unroll
        for (int k = 0; k < MBLK; ++k) {
          float en = EXP2(-ds2[k]);
          dacc[k] = fmaf(en, ur.y, dacc[k]);
          if (MODE == 1) { float e2 = en * en; racc[k] = fmaf(e2 * e2, ur.x, racc[k]); }
        }
      }
    }
  }

  size_t base = ((size_t)mseg * NB + b) * NPTS + n0;
  if (MODE == 2) {
#pragma unroll
    for (int k = 0; k < MBLK; ++k) dacc[k] = rrsum;
  }
  *(float4*)&dbufP[base]     = make_float4(dacc[0], dacc[1], dacc[2], dacc[3]);
  *(float4*)&dbufP[base + 4] = make_float4(dacc[4], dacc[5], dacc[6], dacc[7]);
  if (MODE >= 1) {
    *(float4*)&rsumP[base]     = make_float4(racc[0], racc[1], racc[2], racc[3]);
    *(float4*)&rsumP[base + 4] = make_float4(racc[4], racc[5], racc[6], racc[7]);
  }
}

// ---------------------------------------------------------------------------
// B kernel: s0[m] = sum_n a*e_i, s1[m] = sum_n a*e_i*dist (de-scaled once).
// LVL0: i=9 (e=1, sc=1): s0 = sum a (wave reduce), sqrt-only loop.
// ---------------------------------------------------------------------------
template<int LVL0, bool PSKIP, int CHUNK>
__global__ __launch_bounds__(TPB) void b_kernel(
    const float4* __restrict__ x1p, const float* __restrict__ abuf,
    const float4* __restrict__ x2p,
    float* __restrict__ s0P, float* __restrict__ s1P,
    float sc, float inv_s)
{
  __shared__ float4 x1s[CHUNK];
  __shared__ float  as_[CHUNK];

  const int tid = threadIdx.x;
  const int mchunk = blockIdx.x, nsegi = blockIdx.y, b = blockIdx.z;

  for (int nn = tid; nn < CHUNK; nn += TPB) {
    int n = nsegi * CHUNK + nn;
    float4 p = x1p[(size_t)b * NPTS + n];
    float sx = sc * p.x, sy = sc * p.y, sz = sc * p.z;
    float npv = fmaf(sz, sz, fmaf(sy, sy, sx * sx));
    x1s[nn] = make_float4(-2.f * sx, -2.f * sy, -2.f * sz, npv);
    as_[nn] = abuf[(size_t)b * NPTS + n];
  }
  __syncthreads();

  const int m0 = mchunk * (TPB * MBLK) + tid * MBLK;
  float qx[MBLK], qy[MBLK], qz[MBLK], nq[MBLK], s0a[MBLK], s1a[MBLK];
#pragma unroll
  for (int k = 0; k < MBLK; ++k) {
    float4 q = x2p[(size_t)b * NPTS + m0 + k];
    qx[k] = sc * q.x; qy[k] = sc * q.y; qz[k] = sc * q.z;
    nq[k] = fmaf(qz[k], qz[k], fmaf(qy[k], qy[k], qx[k] * qx[k]));
    s0a[k] = 0.f; s1a[k] = 0.f;
  }

  float asum = 0.f;
  if (LVL0) {                // s0 = sum_n a (constant across owned m)
    float v = 0.f;
    for (int l = (tid & 63); l < CHUNK; l += 64) v += as_[l];
#pragma unroll
    for (int off = 1; off < 64; off <<= 1) v += __shfl_xor(v, off);
    asum = v;
  }

#pragma unroll 2
  for (int nn = 0; nn < CHUNK; ++nn) {
    float4 p = x1s[nn];
    float av = as_[nn];
    float ds2[MBLK];
#pragma unroll
    for (int k = 0; k < MBLK; ++k)
      ds2[k] = fmaf(p.x, qx[k], fmaf(p.y, qy[k], fmaf(p.z, qz[k], nq[k] + p.w)));
    if (LVL0) {
#pragma unroll
      for (int k = 0; k < MBLK; ++k)
        s1a[k] = fmaf(av, SQRTF(__builtin_fabsf(ds2[k])), s1a[k]);
    } else {
      bool go = true;
      if (PSKIP) {
        float dmin = fminf(fminf(fminf(ds2[0], ds2[1]), fminf(ds2[2], ds2[3])),
                           fminf(fminf(ds2[4], ds2[5]), fminf(ds2[6], ds2[7])));
        go = dmin < 126.f;
      }
      if (go) {
#pragma unroll
        for (int k = 0; k < MBLK; ++k) {
          float tt = av * EXP2(-ds2[k]);
          s0a[k] += tt;
          s1a[k] = fmaf(tt, SQRTF(__builtin_fabsf(ds2[k])), s1a[k]);
        }
      }
    }
  }

  size_t base = ((size_t)nsegi * NB + b) * NPTS + m0;
  if (LVL0) {
#pragma unroll
    for (int k = 0; k < MBLK; ++k) s0a[k] = asum;
  }
  *(float4*)&s0P[base]     = make_float4(s0a[0], s0a[1], s0a[2], s0a[3]);
  *(float4*)&s0P[base + 4] = make_float4(s0a[4], s0a[5], s0a[6], s0a[7]);
  *(float4*)&s1P[base]     = make_float4(s1a[0] * inv_s, s1a[1] * inv_s,
                                         s1a[2] * inv_s, s1a[3] * inv_s);
  *(float4*)&s1P[base + 4] = make_float4(s1a[4] * inv_s, s1a[5] * inv_s,
                                         s1a[6] * inv_s, s1a[7] * inv_s);
}

// ---------------------------------------------------------------------------
// R1 (wide): block = 32 elements x 8 seg-slices (256 thr); coalesced plane
// sums; slice 0 does the remainL recurrence and a_i = rl/(denom+eps).
// ---------------------------------------------------------------------------
template<int NSEG>
__global__ __launch_bounds__(256) void r1_kernel(
    const float* __restrict__ dbufP, const float* __restrict__ rsumP,
    float* __restrict__ lbuf, float* __restrict__ dtot,
    float* __restrict__ abuf, int iter)
{
  constexpr int SL = 8, EPB = 32, PPS = NSEG / SL;
  __shared__ float redD[SL][EPB];
  __shared__ float redR[SL][EPB];

  const int e  = threadIdx.x & (EPB - 1);
  const int sl = threadIdx.x / EPB;
  const int idx = blockIdx.x * EPB + e;
  const size_t plane = (size_t)NB * NPTS;

  float ad = 0.f, ar = 0.f;
#pragma unroll
  for (int s = 0; s < PPS; ++s)
    ad += dbufP[(size_t)(sl * PPS + s) * plane + idx];
  if (iter > 0) {
#pragma unroll
    for (int s = 0; s < PPS; ++s)
      ar += rsumP[(size_t)(sl * PPS + s) * plane + idx];
  }
  redD[sl][e] = ad;
  redR[sl][e] = ar;
  __syncthreads();

  if (sl == 0) {
    float dnew = 0.f, rs = 0.f;
#pragma unroll
    for (int s = 0; s < SL; ++s) { dnew += redD[s][e]; rs += redR[s][e]; }
    float rl = 1.f;
    if (iter > 0) {
      float rlp = lbuf[idx];
      float ap  = rlp * RCPF(dtot[idx] + EPSC);
      rl = fmaxf(rlp - ap * rs, 0.f);
    }
    lbuf[idx] = rl;
    dtot[idx] = dnew;
    abuf[idx] = rl * RCPF(dnew + EPSC);
  }
}

// ---------------------------------------------------------------------------
// R2 (wide): u = rr*min(rr/(rr*s0+eps),1); urbuf = (u, rr'); cost partial ->
// one atomicAdd(out + b) per block.
// ---------------------------------------------------------------------------
template<int NSEG, bool LAST>
__global__ __launch_bounds__(256) void r2_kernel(
    const float* __restrict__ s0P, const float* __restrict__ s1P,
    float2* __restrict__ urbuf, float* __restrict__ out, int iter)
{
  constexpr int SL = 8, EPB = 32, PPS = NSEG / SL;
  __shared__ float redA[SL][EPB];
  __shared__ float redB[SL][EPB];

  const int e  = threadIdx.x & (EPB - 1);
  const int sl = threadIdx.x / EPB;
  const int idx = blockIdx.x * EPB + e;
  const int b = idx >> 12;
  const size_t plane = (size_t)NB * NPTS;

  float a0 = 0.f, a1 = 0.f;
#pragma unroll
  for (int s = 0; s < PPS; ++s) {
    a0 += s0P[(size_t)(sl * PPS + s) * plane + idx];
    a1 += s1P[(size_t)(sl * PPS + s) * plane + idx];
  }
  redA[sl][e] = a0;
  redB[sl][e] = a1;
  __syncthreads();

  float cpart = 0.f;
  if (sl == 0) {
    float s0 = 0.f, s1 = 0.f;
#pragma unroll
    for (int s = 0; s < SL; ++s) { s0 += redA[s][e]; s1 += redB[s][e]; }
    float rr    = (iter == 0) ? 1.f : urbuf[idx].y;
    float sumr  = fmaf(rr, s0, EPSC);
    float ratio = fminf(rr * RCPF(sumr), 1.f);
    float u     = rr * ratio;
    if (!LAST) urbuf[idx] = make_float2(u, fmaxf(rr - u * s0, 0.f));
    cpart = u * s1;
  }
  __syncthreads();
  if (sl == 0) redA[0][e] = cpart;
  __syncthreads();
  if (threadIdx.x == 0) {
    float acc = 0.f;
#pragma unroll
    for (int j = 0; j < EPB; ++j) acc += redA[0][j];
    atomicAdd(out + b, acc);
  }
}

// ---------------------------------------------------------------------------
template<int NSEG>
static void run_all(const float* x1, const float* x2, float* out, float* ws,
                    hipStream_t stream)
{
  constexpr int CHUNK = NPTS / NSEG;
  const size_t plane = (size_t)NB * NPTS;

  float*  bufA = ws;                                      // NSEG planes
  float*  bufB = bufA + (size_t)NSEG * plane;             // NSEG planes
  float4* x1p  = (float4*)(bufB + (size_t)NSEG * plane);  // 4 planes
  float4* x2p  = x1p + plane;                             // 4 planes
  float*  dtot = (float*)(x2p + plane);
  float*  lbuf = dtot + plane;
  float*  abuf = lbuf + plane;
  float2* urbuf = (float2*)(abuf + plane);                // 2 planes

  const double L2E = 1.4426950408889634074;
  const double lv[10] = {-16384.0, -4096.0, -1024.0, -256.0, -64.0,
                         -16.0, -4.0, -1.0, -0.25, 0.0};
  float scl[10], inv_s[10];
  for (int i = 0; i < 10; ++i) {
    double c2 = lv[i] * L2E;
    scl[i]   = (i == 9) ? 1.f : (float)sqrt(-c2);
    inv_s[i] = (i == 9) ? 1.f : (float)(1.0 / sqrt(-c2));
  }

  dim3 gmain(NPTS / (TPB * MBLK), NSEG, NB), bmain(TPB);
  dim3 gr(NB * NPTS / 32), br(256);

  sort_kernel<<<dim3(2, NB), bmain, 0, stream>>>(x1, x2, x1p, x2p);

  // A_0: denom_0 partials (level -16384), zero out[]
  ca_kernel<0, true, CHUNK><<<gmain, bmain, 0, stream>>>(
      x2p, x1p, urbuf, bufA, bufB, out, scl[0]);

  for (int i = 0; i < 10; ++i) {
    r1_kernel<NSEG><<<gr, br, 0, stream>>>(bufA, bufB, lbuf, dtot, abuf, i);

    // B_i: PSKIP only where whole-wave skips actually fire (levels <= -1024)
    if (i <= 2)
      b_kernel<0, true, CHUNK><<<gmain, bmain, 0, stream>>>(
          x1p, abuf, x2p, bufA, bufB, scl[i], inv_s[i]);
    else if (i <= 8)
      b_kernel<0, false, CHUNK><<<gmain, bmain, 0, stream>>>(
          x1p, abuf, x2p, bufA, bufB, scl[i], inv_s[i]);
    else
      b_kernel<1, false, CHUNK><<<gmain, bmain, 0, stream>>>(
          x1p, abuf, x2p, bufA, bufB, 1.f, 1.f);

    if (i < 9)
      r2_kernel<NSEG, false><<<gr, br, 0, stream>>>(bufA, bufB, urbuf, out, i);
    else
      r2_kernel<NSEG, true><<<gr, br, 0, stream>>>(bufA, bufB, urbuf, out, i);

    // CA_i stages level i+1: PSKIP while level_{i+1} <= -1024 (i <= 1)
    if (i <= 1)
      ca_kernel<1, true, CHUNK><<<gmain, bmain, 0, stream>>>(
          x2p, x1p, urbuf, bufA, bufB, out, scl[i + 1]);
    else if (i <= 7)
      ca_kernel<1, false, CHUNK><<<gmain, bmain, 0, stream>>>(
          x2p, x1p, urbuf, bufA, bufB, out, scl[i + 1]);
    else if (i == 8)
      ca_kernel<2, false, CHUNK><<<gmain, bmain, 0, stream>>>(
          x2p, x1p, urbuf, bufA, bufB, out, scl[8]);
  }
}

extern "C" void kernel_launch(void* const* d_in, const int* in_sizes, int n_in,
                              void* d_out, int out_size, void* d_ws, size_t ws_size,
                              hipStream_t stream) {
  const float* x1 = (const float*)d_in[0];
  const float* x2 = (const float*)d_in[1];
  float* out = (float*)d_out;
  float* ws  = (float*)d_ws;

  const size_t plane = (size_t)NB * NPTS;
  auto need = [&](int nseg) {
    return (size_t)(2 * nseg + 13) * plane * sizeof(float);
  };

  if (ws_size >= need(32))      run_all<32>(x1, x2, out, ws, stream);
  else                          run_all<16>(x1, x2, out, ws, stream);
}